// Round 4
// baseline (558.179 us; speedup 1.0000x reference)
//
#include <hip/hip_runtime.h>
#include <hip/hip_fp16.h>

#define NN 50000
#define NE 800000
#define D 128
#define NB 196        // ceil(50000/256)
#define FILL_BLOCKS 1024
#define GEMM_BLOCKS 3128   // 782 * 4
#define RNG 6250      // NN / 8 (dst range per XCD)
#define ESL 6250      // NE / 128 (edge slice per fill-rank)

typedef _Float16 half8_t __attribute__((ext_vector_type(8)));
typedef _Float16 half4_t __attribute__((ext_vector_type(4)));
typedef float f32x4 __attribute__((ext_vector_type(4)));

// ---------------- K0: init counters + summary slots + W transpose to half ----------------
__global__ void k_init(int* cnt1, int* cnt2, float* s1, float* s2,
                       const float* __restrict__ W1, const float* __restrict__ W2,
                       _Float16* wt1, _Float16* wt2) {
    int i = blockIdx.x * blockDim.x + threadIdx.x;
    int stride = gridDim.x * blockDim.x;
    for (int j = i; j < NN; j += stride) { cnt1[j] = 0; cnt2[j] = 0; }
    if (i < D) { s1[i] = 0.f; s2[i] = 0.f; }
    if (i < 16384) {
        int n = i >> 7, k = i & 127;
        wt1[n * 128 + k] = (_Float16)W1[k * 128 + n];
        wt2[n * 128 + k] = (_Float16)W2[k * 128 + n];
    }
}

// ---------------- K1: in-degree histogram, XCD-binned ----------------
__global__ void k_count(const int* __restrict__ dst1, const int* __restrict__ dst2,
                        int* cnt1, int* cnt2) {
    int r = blockIdx.x & 7;
    int rank = blockIdx.x >> 3;          // 0..127
    unsigned lo = r * RNG;
    int base = rank * ESL;
    for (int e = base + threadIdx.x; e < base + ESL; e += 256) {
        int d1 = dst1[e];
        if ((unsigned)(d1 - lo) < RNG) atomicAdd(&cnt1[d1], 1);
        int d2 = dst2[e];
        if ((unsigned)(d2 - lo) < RNG) atomicAdd(&cnt2[d2], 1);
    }
}

// ---------------- K2a: per-block partial sums of counts (both graphs) ----------------
__global__ void k_part(const int* __restrict__ cnt1, const int* __restrict__ cnt2,
                       int* part1, int* part2) {
    __shared__ int sm1[256], sm2[256];
    int t = threadIdx.x;
    int idx = blockIdx.x * 256 + t;
    int v1 = (idx < NN) ? cnt1[idx] : 0;
    int v2 = (idx < NN) ? cnt2[idx] : 0;
    sm1[t] = v1; sm2[t] = v2;
    __syncthreads();
    for (int off = 128; off > 0; off >>= 1) {
        if (t < off) { sm1[t] += sm1[t + off]; sm2[t] += sm2[t + off]; }
        __syncthreads();
    }
    if (t == 0) { part1[blockIdx.x] = sm1[0]; part2[blockIdx.x] = sm2[0]; }
}

// ---------------- K2b: exclusive scan of block partials (one block) ----------------
__global__ void k_scanp(int* part1, int* part2) {
    __shared__ int sm1[256], sm2[256];
    int t = threadIdx.x;
    int v1 = (t < NB) ? part1[t] : 0;
    int v2 = (t < NB) ? part2[t] : 0;
    sm1[t] = v1; sm2[t] = v2;
    __syncthreads();
    for (int off = 1; off < 256; off <<= 1) {
        int a1 = (t >= off) ? sm1[t - off] : 0;
        int a2 = (t >= off) ? sm2[t - off] : 0;
        __syncthreads();
        sm1[t] += a1; sm2[t] += a2;
        __syncthreads();
    }
    if (t < NB) { part1[t] = sm1[t] - v1; part2[t] = sm2[t] - v2; }
}

// ---------------- K2c: apply block offsets -> rp, cur, dinv ----------------
__global__ void k_apply(const int* __restrict__ cnt1, const int* __restrict__ cnt2,
                        const int* __restrict__ part1, const int* __restrict__ part2,
                        int* rp1, int* rp2, int* cur1, int* cur2,
                        float* dinv1, float* dinv2) {
    __shared__ int sm1[256], sm2[256];
    int b = blockIdx.x, t = threadIdx.x;
    int idx = b * 256 + t;
    int v1 = (idx < NN) ? cnt1[idx] : 0;
    int v2 = (idx < NN) ? cnt2[idx] : 0;
    sm1[t] = v1; sm2[t] = v2;
    __syncthreads();
    for (int off = 1; off < 256; off <<= 1) {
        int a1 = (t >= off) ? sm1[t - off] : 0;
        int a2 = (t >= off) ? sm2[t - off] : 0;
        __syncthreads();
        sm1[t] += a1; sm2[t] += a2;
        __syncthreads();
    }
    int e1 = sm1[t] - v1 + part1[b];  // exclusive prefix
    int e2 = sm2[t] - v2 + part2[b];
    if (idx < NN) {
        rp1[idx] = e1; cur1[idx] = e1; dinv1[idx] = rsqrtf((float)(v1 + 1));
        rp2[idx] = e2; cur2[idx] = e2; dinv2[idx] = rsqrtf((float)(v2 + 1));
    } else if (idx == NN) {
        rp1[NN] = e1; rp2[NN] = e2;
    }
}

// ---------------- K3+K4 merged: fill-first (blocks 0..1023), then 4 GEMMs ----------------
// Dispatch structure from R2 (merged; fill blocks own all 4-blocks/CU slots first, GEMM
// backfills as fills retire -> tail overlap, no co-residency thrash). GEMM body from R3
// (no W staging, no barriers, w-fragments direct from L2-resident 32KB WT).
// ST is deliberately declared 8 slices (34816 B, only 0..3 used) to PIN occupancy at
// 4 blocks/CU -> preserves R2's pure-fill startup schedule (R1 showed 50/50 co-residency
// regresses 162->263us).
__launch_bounds__(256)
__global__ void k_fill_gemm(const int* __restrict__ src1, const int* __restrict__ dst1,
                            const int* __restrict__ src2, const int* __restrict__ dst2,
                            int* cur1, int* cur2, int* col1, int* col2,
                            const _Float16* __restrict__ wt1, const _Float16* __restrict__ wt2,
                            const float* __restrict__ x,
                            const float* __restrict__ mp1, const float* __restrict__ mn1,
                            const float* __restrict__ mp2, const float* __restrict__ mn2,
                            const int* __restrict__ perm1, const int* __restrict__ perm2,
                            const float* __restrict__ dinv1, const float* __restrict__ dinv2,
                            _Float16* xwi1, _Float16* xwi2) {
    __shared__ __align__(16) _Float16 ST[8][16][136];   // 34816 B occupancy pin; slices 0..3 used
    int t = threadIdx.x;
    int bid = blockIdx.x;

    if (bid < FILL_BLOCKS) {
        // ---- FILL block: r = bid&7 selects dst range (XCD-local atomics) ----
        int r = bid & 7;
        int rank = bid >> 3;              // 0..127
        unsigned lo = r * RNG;
        int base = rank * ESL;
        for (int e = base + t; e < base + ESL; e += 256) {
            int d1 = dst1[e];
            if ((unsigned)(d1 - lo) < RNG) {
                int p = atomicAdd(&cur1[d1], 1);
                col1[p] = src1[e];
            }
            int d2 = dst2[e];
            if ((unsigned)(d2 - lo) < RNG) {
                int p = atomicAdd(&cur2[d2], 1);
                col2[p] = src2[e];
            }
        }
        return;
    }

    // ---- GEMM block (staging-free, barrier-free) ----
    int g = bid - FILL_BLOCKS;             // 0..3127
    int which = g / 782;                   // 0 = pos1, 1 = neg1, 2 = pos2, 3 = neg2
    int bx = g - which * 782;
    const _Float16* wt = (which < 2) ? wt1 : wt2;
    const float* mask = (which == 0) ? mp1 : (which == 1) ? mn1 : (which == 2) ? mp2 : mn2;
    const int* perm = (which == 1) ? perm1 : (which == 3) ? perm2 : nullptr;
    const float* dinv = (which < 2) ? dinv1 : dinv2;
    _Float16* out = ((which < 2) ? xwi1 : xwi2) + ((which & 1) ? 128 : 0);

    int wave = t >> 6;
    int lane = t & 63;
    int quad = lane >> 4;
    int m = lane & 15;
    int tile = bx * 4 + wave;
    if (tile * 16 >= NN) return;           // no barriers in this path -> safe early return

    int row = tile * 16 + m;
    int grow = perm ? perm[row] : row;
    const float* xrow = x + (long)grow * D;
    const float* mrow = mask + (long)grow * D;

    half8_t a[4];
    #pragma unroll
    for (int kk = 0; kk < 4; kk++) {
        int k0 = kk * 32 + quad * 8;
        float4 xa = *(const float4*)(xrow + k0);
        float4 xb = *(const float4*)(xrow + k0 + 4);
        float4 ma = *(const float4*)(mrow + k0);
        float4 mb = *(const float4*)(mrow + k0 + 4);
        a[kk][0] = (_Float16)(xa.x * ma.x);
        a[kk][1] = (_Float16)(xa.y * ma.y);
        a[kk][2] = (_Float16)(xa.z * ma.z);
        a[kk][3] = (_Float16)(xa.w * ma.w);
        a[kk][4] = (_Float16)(xb.x * mb.x);
        a[kk][5] = (_Float16)(xb.y * mb.y);
        a[kk][6] = (_Float16)(xb.z * mb.z);
        a[kk][7] = (_Float16)(xb.w * mb.w);
    }

    // Swapped operands: A = W-fragment (out-col), B = x-fragment (x-row).
    f32x4 accs[8];
    #pragma unroll
    for (int nt = 0; nt < 8; nt++) {
        const _Float16* wrow = wt + (nt * 16 + m) * 128 + quad * 8;
        f32x4 acc = {0.f, 0.f, 0.f, 0.f};
        #pragma unroll
        for (int kk = 0; kk < 4; kk++) {
            half8_t w = *(const half8_t*)(wrow + kk * 32);
            acc = __builtin_amdgcn_mfma_f32_16x16x32_f16(w, a[kk], acc, 0, 0, 0);
        }
        accs[nt] = acc;
    }

    // Per-wave LDS transpose epilogue (wave-private slice -> no sync needed).
    float ds = dinv[tile * 16 + m];        // one row per lane
    _Float16* st = &ST[wave][0][0];

    #pragma unroll
    for (int nt = 0; nt < 8; nt++) {
        half4_t h;
        h[0] = (_Float16)(accs[nt][0] * ds);
        h[1] = (_Float16)(accs[nt][1] * ds);
        h[2] = (_Float16)(accs[nt][2] * ds);
        h[3] = (_Float16)(accs[nt][3] * ds);
        *(half4_t*)(st + m * 136 + nt * 16 + quad * 4) = h;
    }
    // Read back row-contiguous; every store instr = 16 rows x 64B full aligned lines.
    #pragma unroll
    for (int p = 0; p < 4; p++) {
        int r = lane & 15;
        int cc = (lane >> 4) + p * 4;       // 16B chunk index 0..15
        half8_t v = *(const half8_t*)(st + r * 136 + cc * 8);
        *(half8_t*)(out + (long)(tile * 16 + r) * 256 + cc * 8) = v;
    }
}

// ---------------- K5: CSR gather aggregation + bias + ReLU (no atomics) ----------------
__launch_bounds__(256)
__global__ void k_agg(const _Float16* __restrict__ xwi1, const _Float16* __restrict__ xwi2,
                      const int* __restrict__ rp1, const int* __restrict__ col1,
                      const float* __restrict__ dinv1,
                      const int* __restrict__ rp2, const int* __restrict__ col2,
                      const float* __restrict__ dinv2,
                      const float* __restrict__ b1, const float* __restrict__ b2,
                      float* out) {
    int g = blockIdx.y;
    const _Float16* xwi = g ? xwi2 : xwi1;
    const int* rp = g ? rp2 : rp1;
    const int* col = g ? col2 : col1;
    const float* dinv = g ? dinv2 : dinv1;
    const float* bias = g ? b2 : b1;
    float* pos_out = out + (g ? 12800128L : 0L);
    float* neg_out = out + (g ? 19200128L : 6400000L);

    int t = threadIdx.x;
    int wave = t >> 6, lane = t & 63;
    int i = blockIdx.x * 4 + wave;
    if (i >= NN) return;
    int j4 = lane * 4;

    half4_t sv = *(const half4_t*)(xwi + (long)i * 256 + j4);
    float a0 = (float)sv[0], a1 = (float)sv[1], a2 = (float)sv[2], a3 = (float)sv[3];
    int e0 = rp[i], e1 = rp[i + 1];
    int e = e0;
    for (; e + 8 <= e1; e += 8) {
        int s0 = col[e + 0], s1 = col[e + 1], s2 = col[e + 2], s3 = col[e + 3];
        int s4 = col[e + 4], s5 = col[e + 5], s6 = col[e + 6], s7 = col[e + 7];
        half4_t v0 = *(const half4_t*)(xwi + (long)s0 * 256 + j4);
        half4_t v1 = *(const half4_t*)(xwi + (long)s1 * 256 + j4);
        half4_t v2 = *(const half4_t*)(xwi + (long)s2 * 256 + j4);
        half4_t v3 = *(const half4_t*)(xwi + (long)s3 * 256 + j4);
        half4_t v4 = *(const half4_t*)(xwi + (long)s4 * 256 + j4);
        half4_t v5 = *(const half4_t*)(xwi + (long)s5 * 256 + j4);
        half4_t v6 = *(const half4_t*)(xwi + (long)s6 * 256 + j4);
        half4_t v7 = *(const half4_t*)(xwi + (long)s7 * 256 + j4);
        a0 += (float)v0[0] + (float)v1[0] + (float)v2[0] + (float)v3[0]
            + (float)v4[0] + (float)v5[0] + (float)v6[0] + (float)v7[0];
        a1 += (float)v0[1] + (float)v1[1] + (float)v2[1] + (float)v3[1]
            + (float)v4[1] + (float)v5[1] + (float)v6[1] + (float)v7[1];
        a2 += (float)v0[2] + (float)v1[2] + (float)v2[2] + (float)v3[2]
            + (float)v4[2] + (float)v5[2] + (float)v6[2] + (float)v7[2];
        a3 += (float)v0[3] + (float)v1[3] + (float)v2[3] + (float)v3[3]
            + (float)v4[3] + (float)v5[3] + (float)v6[3] + (float)v7[3];
    }
    for (; e + 4 <= e1; e += 4) {
        int s0 = col[e + 0], s1 = col[e + 1], s2 = col[e + 2], s3 = col[e + 3];
        half4_t v0 = *(const half4_t*)(xwi + (long)s0 * 256 + j4);
        half4_t v1 = *(const half4_t*)(xwi + (long)s1 * 256 + j4);
        half4_t v2 = *(const half4_t*)(xwi + (long)s2 * 256 + j4);
        half4_t v3 = *(const half4_t*)(xwi + (long)s3 * 256 + j4);
        a0 += (float)v0[0] + (float)v1[0] + (float)v2[0] + (float)v3[0];
        a1 += (float)v0[1] + (float)v1[1] + (float)v2[1] + (float)v3[1];
        a2 += (float)v0[2] + (float)v1[2] + (float)v2[2] + (float)v3[2];
        a3 += (float)v0[3] + (float)v1[3] + (float)v2[3] + (float)v3[3];
    }
    for (; e < e1; e++) {
        int s = col[e];
        half4_t v = *(const half4_t*)(xwi + (long)s * 256 + j4);
        a0 += (float)v[0]; a1 += (float)v[1]; a2 += (float)v[2]; a3 += (float)v[3];
    }
    float di = dinv[i];
    int jj = (lane < 32) ? j4 : (j4 - 128);
    const f32x4* bp = (const f32x4*)(bias + jj);
    f32x4 bv = *bp;
    f32x4 o;
    o[0] = fmaxf(0.f, di * a0 + bv[0]);
    o[1] = fmaxf(0.f, di * a1 + bv[1]);
    o[2] = fmaxf(0.f, di * a2 + bv[2]);
    o[3] = fmaxf(0.f, di * a3 + bv[3]);
    float* dst = ((lane < 32) ? pos_out : neg_out) + (long)i * D + jj;
    __builtin_nontemporal_store(o, (f32x4*)dst);
}

// ---------------- K6: summary mean over pos_h ----------------
__launch_bounds__(256)
__global__ void k_sum(const float* __restrict__ pos1, const float* __restrict__ pos2,
                      float* s1, float* s2) {
    int g = blockIdx.y;
    const float* pos = g ? pos2 : pos1;
    float* s = g ? s2 : s1;
    int t = threadIdx.x;
    int rg = t >> 5;
    int j = (t & 31) * 4;
    float4 acc = {0.f, 0.f, 0.f, 0.f};
    for (int i = blockIdx.x * 8 + rg; i < NN; i += gridDim.x * 8) {
        float4 v = *(const float4*)(pos + (long)i * D + j);
        acc.x += v.x; acc.y += v.y; acc.z += v.z; acc.w += v.w;
    }
    __shared__ float sm[8][128];
    sm[rg][j + 0] = acc.x;
    sm[rg][j + 1] = acc.y;
    sm[rg][j + 2] = acc.z;
    sm[rg][j + 3] = acc.w;
    __syncthreads();
    if (t < 128) {
        float v = 0.f;
        for (int r = 0; r < 8; r++) v += sm[r][t];
        atomicAdd(&s[t], v * (1.0f / NN));
    }
}

extern "C" void kernel_launch(void* const* d_in, const int* in_sizes, int n_in,
                              void* d_out, int out_size, void* d_ws, size_t ws_size,
                              hipStream_t stream) {
    const float* x   = (const float*)d_in[0];
    const float* W1  = (const float*)d_in[1];
    const float* b1  = (const float*)d_in[2];
    const float* W2  = (const float*)d_in[3];
    const float* b2  = (const float*)d_in[4];
    const float* mp1 = (const float*)d_in[5];
    const float* mn1 = (const float*)d_in[6];
    const float* mp2 = (const float*)d_in[7];
    const float* mn2 = (const float*)d_in[8];
    const int* e1 = (const int*)d_in[9];
    const int* e2 = (const int*)d_in[10];
    const int* perm1 = (const int*)d_in[11];
    const int* perm2 = (const int*)d_in[12];
    const int* src1 = e1;       const int* dst1 = e1 + NE;
    const int* src2 = e2;       const int* dst2 = e2 + NE;
    float* out = (float*)d_out;

    // workspace carve
    char* w = (char*)d_ws;
    _Float16* xwi1 = (_Float16*)w; w += (size_t)NN * 256 * 2;  // 25.6 MB interleaved
    _Float16* xwi2 = (_Float16*)w; w += (size_t)NN * 256 * 2;
    int* cnt1 = (int*)w;  w += (size_t)NN * 4;
    int* cnt2 = (int*)w;  w += (size_t)NN * 4;
    int* cur1 = (int*)w;  w += (size_t)NN * 4;
    int* cur2 = (int*)w;  w += (size_t)NN * 4;
    int* rp1 = (int*)w;   w += (size_t)(NN + 4) * 4;
    int* rp2 = (int*)w;   w += (size_t)(NN + 4) * 4;
    int* col1 = (int*)w;  w += (size_t)NE * 4;
    int* col2 = (int*)w;  w += (size_t)NE * 4;
    float* dinv1 = (float*)w; w += (size_t)NN * 4;
    float* dinv2 = (float*)w; w += (size_t)NN * 4;
    int* part1 = (int*)w; w += (size_t)256 * 4;
    int* part2 = (int*)w; w += (size_t)256 * 4;
    _Float16* wt1 = (_Float16*)w; w += (size_t)D * D * 2;   // 32 KB transposed half W1
    _Float16* wt2 = (_Float16*)w; w += (size_t)D * D * 2;

    float* s1 = out + 12800000L;
    float* s2 = out + 25600128L;
    const float* pos1 = out;
    const float* pos2 = out + 12800128L;

    k_init<<<dim3(256), 256, 0, stream>>>(cnt1, cnt2, s1, s2, W1, W2, wt1, wt2);
    k_count<<<dim3(1024), 256, 0, stream>>>(dst1, dst2, cnt1, cnt2);
    k_part<<<dim3(NB), 256, 0, stream>>>(cnt1, cnt2, part1, part2);
    k_scanp<<<dim3(1), 256, 0, stream>>>(part1, part2);
    k_apply<<<dim3(NB), 256, 0, stream>>>(cnt1, cnt2, part1, part2,
                                          rp1, rp2, cur1, cur2, dinv1, dinv2);
    k_fill_gemm<<<dim3(FILL_BLOCKS + GEMM_BLOCKS), 256, 0, stream>>>(
        src1, dst1, src2, dst2, cur1, cur2, col1, col2, wt1, wt2,
        x, mp1, mn1, mp2, mn2, perm1, perm2, dinv1, dinv2, xwi1, xwi2);
    k_agg<<<dim3(12500, 2), 256, 0, stream>>>(xwi1, xwi2,
                                              rp1, col1, dinv1, rp2, col2, dinv2,
                                              b1, b2, out);
    k_sum<<<dim3(128, 2), 256, 0, stream>>>(pos1, pos2, s1, s2);
}

// Round 5
// 529.646 us; speedup vs baseline: 1.0539x; 1.0539x over previous
//
#include <hip/hip_runtime.h>
#include <hip/hip_fp16.h>

#define NN 50000
#define NE 800000
#define D 128
#define NB 196        // ceil(50000/256)
#define FILL_BLOCKS 1024
#define GEMM_BLOCKS 3128   // 782 * 4
#define RNG 6250      // NN / 8 (dst range per XCD)
#define BCAP 131072   // per-bucket capacity (expected ~100K, sigma ~300)

typedef _Float16 half8_t __attribute__((ext_vector_type(8)));
typedef _Float16 half4_t __attribute__((ext_vector_type(4)));
typedef float f32x4 __attribute__((ext_vector_type(4)));

// ---------------- K0: init counters + summary slots + bucket counters ----------------
__global__ void k_init(int* cnt1, int* cnt2, float* s1, float* s2, int* bcnt) {
    int i = blockIdx.x * blockDim.x + threadIdx.x;
    int stride = gridDim.x * blockDim.x;
    for (int j = i; j < NN; j += stride) { cnt1[j] = 0; cnt2[j] = 0; }
    if (i < D) { s1[i] = 0.f; s2[i] = 0.f; }
    if (i < 16) bcnt[i] = 0;
}

// ---------------- K1: bucket edges by dst range (each edge read ONCE) ----------------
// Replaces the 8x XCD read-amplification of count+fill scans: one 12.8MB pass that
// partitions (s,d) into 8 dst-range buckets per graph. LDS-aggregated counts -> only
// 16 global atomics per block (no hot-counter contention). Downstream passes then read
// only their XCD-local bucket with zero discard.
__global__ void k_bucket(const int* __restrict__ src1, const int* __restrict__ dst1,
                         const int* __restrict__ src2, const int* __restrict__ dst2,
                         int* bcnt,
                         int* bs1, int* bd1, int* bs2, int* bd2) {
    __shared__ int lcnt[16], lpos[16], gbase[16];
    int t = threadIdx.x;
    if (t < 16) { lcnt[t] = 0; lpos[t] = 0; }
    __syncthreads();

    int e0 = blockIdx.x * 256 + t;
    // static-index stash (rule: runtime-indexed arrays go to scratch)
    int s1v0=0,d1v0=0,s2v0=0,d2v0=0, s1v1=0,d1v1=0,s2v1=0,d2v1=0;
    int s1v2=0,d1v2=0,s2v2=0,d2v2=0, s1v3=0,d1v3=0,s2v3=0,d2v3=0;
    bool v0 = (e0 + 0 * 262144) < NE;
    bool v1 = (e0 + 1 * 262144) < NE;
    bool v2 = (e0 + 2 * 262144) < NE;
    bool v3 = (e0 + 3 * 262144) < NE;
    if (v0) { int e = e0;             s1v0 = src1[e]; d1v0 = dst1[e]; s2v0 = src2[e]; d2v0 = dst2[e]; }
    if (v1) { int e = e0 + 262144;    s1v1 = src1[e]; d1v1 = dst1[e]; s2v1 = src2[e]; d2v1 = dst2[e]; }
    if (v2) { int e = e0 + 2*262144;  s1v2 = src1[e]; d1v2 = dst1[e]; s2v2 = src2[e]; d2v2 = dst2[e]; }
    if (v3) { int e = e0 + 3*262144;  s1v3 = src1[e]; d1v3 = dst1[e]; s2v3 = src2[e]; d2v3 = dst2[e]; }

    // pass 1: local bucket counts
    if (v0) { atomicAdd(&lcnt[d1v0 / RNG], 1); atomicAdd(&lcnt[8 + d2v0 / RNG], 1); }
    if (v1) { atomicAdd(&lcnt[d1v1 / RNG], 1); atomicAdd(&lcnt[8 + d2v1 / RNG], 1); }
    if (v2) { atomicAdd(&lcnt[d1v2 / RNG], 1); atomicAdd(&lcnt[8 + d2v2 / RNG], 1); }
    if (v3) { atomicAdd(&lcnt[d1v3 / RNG], 1); atomicAdd(&lcnt[8 + d2v3 / RNG], 1); }
    __syncthreads();
    if (t < 16) gbase[t] = atomicAdd(&bcnt[t], lcnt[t]);
    __syncthreads();

    // pass 2: place
    #define PLACE(sv, dv) { \
        int r = (dv) / RNG; \
        int p = gbase[r] + atomicAdd(&lpos[r], 1); \
        if (p < BCAP) { bs1[r * BCAP + p] = (sv); bd1[r * BCAP + p] = (dv); } }
    #define PLACE2(sv, dv) { \
        int r = (dv) / RNG; \
        int p = gbase[8 + r] + atomicAdd(&lpos[8 + r], 1); \
        if (p < BCAP) { bs2[r * BCAP + p] = (sv); bd2[r * BCAP + p] = (dv); } }
    if (v0) { PLACE(s1v0, d1v0); PLACE2(s2v0, d2v0); }
    if (v1) { PLACE(s1v1, d1v1); PLACE2(s2v1, d2v1); }
    if (v2) { PLACE(s1v2, d1v2); PLACE2(s2v2, d2v2); }
    if (v3) { PLACE(s1v3, d1v3); PLACE2(s2v3, d2v3); }
    #undef PLACE
    #undef PLACE2
}

// ---------------- K2: in-degree histogram from buckets (XCD-local, no discard) ----------------
__global__ void k_count_b(const int* __restrict__ bcnt,
                          const int* __restrict__ bd1, const int* __restrict__ bd2,
                          int* cnt1, int* cnt2) {
    int b = blockIdx.x & 7;
    int rank = blockIdx.x >> 3;          // 0..127
    int base = b * BCAP;
    int n1 = bcnt[b], n2 = bcnt[8 + b];
    for (int i = rank * 256 + threadIdx.x; i < n1; i += 32768)
        atomicAdd(&cnt1[bd1[base + i]], 1);
    for (int i = rank * 256 + threadIdx.x; i < n2; i += 32768)
        atomicAdd(&cnt2[bd2[base + i]], 1);
}

// ---------------- K2a: per-block partial sums of counts (both graphs) ----------------
__global__ void k_part(const int* __restrict__ cnt1, const int* __restrict__ cnt2,
                       int* part1, int* part2) {
    __shared__ int sm1[256], sm2[256];
    int t = threadIdx.x;
    int idx = blockIdx.x * 256 + t;
    int v1 = (idx < NN) ? cnt1[idx] : 0;
    int v2 = (idx < NN) ? cnt2[idx] : 0;
    sm1[t] = v1; sm2[t] = v2;
    __syncthreads();
    for (int off = 128; off > 0; off >>= 1) {
        if (t < off) { sm1[t] += sm1[t + off]; sm2[t] += sm2[t + off]; }
        __syncthreads();
    }
    if (t == 0) { part1[blockIdx.x] = sm1[0]; part2[blockIdx.x] = sm2[0]; }
}

// ---------------- K2b: exclusive scan of block partials (one block) ----------------
__global__ void k_scanp(int* part1, int* part2) {
    __shared__ int sm1[256], sm2[256];
    int t = threadIdx.x;
    int v1 = (t < NB) ? part1[t] : 0;
    int v2 = (t < NB) ? part2[t] : 0;
    sm1[t] = v1; sm2[t] = v2;
    __syncthreads();
    for (int off = 1; off < 256; off <<= 1) {
        int a1 = (t >= off) ? sm1[t - off] : 0;
        int a2 = (t >= off) ? sm2[t - off] : 0;
        __syncthreads();
        sm1[t] += a1; sm2[t] += a2;
        __syncthreads();
    }
    if (t < NB) { part1[t] = sm1[t] - v1; part2[t] = sm2[t] - v2; }
}

// ---------------- K2c: apply block offsets -> rp, cur, dinv ----------------
__global__ void k_apply(const int* __restrict__ cnt1, const int* __restrict__ cnt2,
                        const int* __restrict__ part1, const int* __restrict__ part2,
                        int* rp1, int* rp2, int* cur1, int* cur2,
                        float* dinv1, float* dinv2) {
    __shared__ int sm1[256], sm2[256];
    int b = blockIdx.x, t = threadIdx.x;
    int idx = b * 256 + t;
    int v1 = (idx < NN) ? cnt1[idx] : 0;
    int v2 = (idx < NN) ? cnt2[idx] : 0;
    sm1[t] = v1; sm2[t] = v2;
    __syncthreads();
    for (int off = 1; off < 256; off <<= 1) {
        int a1 = (t >= off) ? sm1[t - off] : 0;
        int a2 = (t >= off) ? sm2[t - off] : 0;
        __syncthreads();
        sm1[t] += a1; sm2[t] += a2;
        __syncthreads();
    }
    int e1 = sm1[t] - v1 + part1[b];  // exclusive prefix
    int e2 = sm2[t] - v2 + part2[b];
    if (idx < NN) {
        rp1[idx] = e1; cur1[idx] = e1; dinv1[idx] = rsqrtf((float)(v1 + 1));
        rp2[idx] = e2; cur2[idx] = e2; dinv2[idx] = rsqrtf((float)(v2 + 1));
    } else if (idx == NN) {
        rp1[NN] = e1; rp2[NN] = e2;
    }
}

// ---------------- K3+K4 merged: fill-first (blocks 0..1023), then 4 GEMMs ----------------
// Dispatch structure + gemm body = R2 exact (measured best, 143us). Fill section now
// reads XCD-local buckets: no range filter, no 8x amplification (~50MB -> 12.8MB reads).
__launch_bounds__(256)
__global__ void k_fill_gemm(const int* __restrict__ bcnt,
                            const int* __restrict__ bs1, const int* __restrict__ bd1,
                            const int* __restrict__ bs2, const int* __restrict__ bd2,
                            int* cur1, int* cur2, int* col1, int* col2,
                            const float* __restrict__ x,
                            const float* __restrict__ W1, const float* __restrict__ W2,
                            const float* __restrict__ mp1, const float* __restrict__ mn1,
                            const float* __restrict__ mp2, const float* __restrict__ mn2,
                            const int* __restrict__ perm1, const int* __restrict__ perm2,
                            const float* __restrict__ dinv1, const float* __restrict__ dinv2,
                            _Float16* xwi1, _Float16* xwi2) {
    __shared__ __align__(16) _Float16 WT[128][136];   // 34816 B -> 4 blocks/CU
    int t = threadIdx.x;
    int bid = blockIdx.x;

    if (bid < FILL_BLOCKS) {
        // ---- FILL block: bucket b = bid&7 (XCD-local atomics), no discard scan ----
        int b = bid & 7;
        int rank = bid >> 3;              // 0..127
        int base = b * BCAP;
        int n1 = bcnt[b], n2 = bcnt[8 + b];
        for (int i = rank * 256 + t; i < n1; i += 32768) {
            int d = bd1[base + i];
            int p = atomicAdd(&cur1[d], 1);
            col1[p] = bs1[base + i];
        }
        for (int i = rank * 256 + t; i < n2; i += 32768) {
            int d = bd2[base + i];
            int p = atomicAdd(&cur2[d], 1);
            col2[p] = bs2[base + i];
        }
        return;
    }

    // ---- GEMM block (R2-exact body) ----
    int g = bid - FILL_BLOCKS;             // 0..3127
    int which = g / 782;                   // 0 = pos1, 1 = neg1, 2 = pos2, 3 = neg2
    int bx = g - which * 782;
    const float* W = (which < 2) ? W1 : W2;
    const float* mask = (which == 0) ? mp1 : (which == 1) ? mn1 : (which == 2) ? mp2 : mn2;
    const int* perm = (which == 1) ? perm1 : (which == 3) ? perm2 : nullptr;
    const float* dinv = (which < 2) ? dinv1 : dinv2;
    _Float16* out = ((which < 2) ? xwi1 : xwi2) + ((which & 1) ? 128 : 0);

    // W staging: column-chunk loads (coalesced) + half8 16B LDS writes (conflict-free).
    #pragma unroll
    for (int i = 0; i < 8; i++) {
        int idx = i * 256 + t;            // 0..2047
        int j = idx & 127;
        int k0 = (idx >> 7) * 8;          // 0,8,...,120
        half8_t h;
        #pragma unroll
        for (int c = 0; c < 8; c++) h[c] = (_Float16)W[(k0 + c) * 128 + j];
        *(half8_t*)(&WT[j][k0]) = h;      // WT[n][k], fp16
    }
    __syncthreads();

    int wave = t >> 6;
    int lane = t & 63;
    int quad = lane >> 4;
    int m = lane & 15;
    int tile = bx * 4 + wave;
    bool active = (tile * 16 < NN);       // no early return: barrier below

    f32x4 accs[8];
    if (active) {
        int row = tile * 16 + m;
        int grow = perm ? perm[row] : row;
        const float* xrow = x + (long)grow * D;
        const float* mrow = mask + (long)grow * D;

        half8_t a[4];
        #pragma unroll
        for (int kk = 0; kk < 4; kk++) {
            int k0 = kk * 32 + quad * 8;
            float4 xa = *(const float4*)(xrow + k0);
            float4 xb = *(const float4*)(xrow + k0 + 4);
            float4 ma = *(const float4*)(mrow + k0);
            float4 mb = *(const float4*)(mrow + k0 + 4);
            a[kk][0] = (_Float16)(xa.x * ma.x);
            a[kk][1] = (_Float16)(xa.y * ma.y);
            a[kk][2] = (_Float16)(xa.z * ma.z);
            a[kk][3] = (_Float16)(xa.w * ma.w);
            a[kk][4] = (_Float16)(xb.x * mb.x);
            a[kk][5] = (_Float16)(xb.y * mb.y);
            a[kk][6] = (_Float16)(xb.z * mb.z);
            a[kk][7] = (_Float16)(xb.w * mb.w);
        }

        // Swapped operands: A = W-fragment (out-col), B = x-fragment (x-row).
        #pragma unroll
        for (int nt = 0; nt < 8; nt++) {
            f32x4 acc = {0.f, 0.f, 0.f, 0.f};
            #pragma unroll
            for (int kk = 0; kk < 4; kk++) {
                half8_t w = *(const half8_t*)(&WT[nt * 16 + m][kk * 32 + quad * 8]);
                acc = __builtin_amdgcn_mfma_f32_16x16x32_f16(w, a[kk], acc, 0, 0, 0);
            }
            accs[nt] = acc;
        }
    }

    // All waves done reading WT -> reuse it as per-wave transpose staging.
    __syncthreads();

    if (active) {
        float ds = dinv[tile * 16 + m];   // one row per lane
        _Float16* st = &WT[0][0] + wave * 2176;   // 16 rows x 136 halves per wave

        #pragma unroll
        for (int nt = 0; nt < 8; nt++) {
            half4_t h;
            h[0] = (_Float16)(accs[nt][0] * ds);
            h[1] = (_Float16)(accs[nt][1] * ds);
            h[2] = (_Float16)(accs[nt][2] * ds);
            h[3] = (_Float16)(accs[nt][3] * ds);
            *(half4_t*)(st + m * 136 + nt * 16 + quad * 4) = h;
        }
        // Read back row-contiguous; every store instr = 16 rows x 64B full aligned lines.
        #pragma unroll
        for (int p = 0; p < 4; p++) {
            int r = lane & 15;
            int cc = (lane >> 4) + p * 4;       // 16B chunk index 0..15
            half8_t v = *(const half8_t*)(st + r * 136 + cc * 8);
            *(half8_t*)(out + (long)(tile * 16 + r) * 256 + cc * 8) = v;
        }
    }
}

// ---------------- K5: CSR gather aggregation + bias + ReLU (no atomics) ----------------
__launch_bounds__(256)
__global__ void k_agg(const _Float16* __restrict__ xwi1, const _Float16* __restrict__ xwi2,
                      const int* __restrict__ rp1, const int* __restrict__ col1,
                      const float* __restrict__ dinv1,
                      const int* __restrict__ rp2, const int* __restrict__ col2,
                      const float* __restrict__ dinv2,
                      const float* __restrict__ b1, const float* __restrict__ b2,
                      float* out) {
    int g = blockIdx.y;
    const _Float16* xwi = g ? xwi2 : xwi1;
    const int* rp = g ? rp2 : rp1;
    const int* col = g ? col2 : col1;
    const float* dinv = g ? dinv2 : dinv1;
    const float* bias = g ? b2 : b1;
    float* pos_out = out + (g ? 12800128L : 0L);
    float* neg_out = out + (g ? 19200128L : 6400000L);

    int t = threadIdx.x;
    int wave = t >> 6, lane = t & 63;
    int i = blockIdx.x * 4 + wave;
    if (i >= NN) return;
    int j4 = lane * 4;

    half4_t sv = *(const half4_t*)(xwi + (long)i * 256 + j4);
    float a0 = (float)sv[0], a1 = (float)sv[1], a2 = (float)sv[2], a3 = (float)sv[3];
    int e0 = rp[i], e1 = rp[i + 1];
    int e = e0;
    for (; e + 8 <= e1; e += 8) {
        int s0 = col[e + 0], s1 = col[e + 1], s2 = col[e + 2], s3 = col[e + 3];
        int s4 = col[e + 4], s5 = col[e + 5], s6 = col[e + 6], s7 = col[e + 7];
        half4_t v0 = *(const half4_t*)(xwi + (long)s0 * 256 + j4);
        half4_t v1 = *(const half4_t*)(xwi + (long)s1 * 256 + j4);
        half4_t v2 = *(const half4_t*)(xwi + (long)s2 * 256 + j4);
        half4_t v3 = *(const half4_t*)(xwi + (long)s3 * 256 + j4);
        half4_t v4 = *(const half4_t*)(xwi + (long)s4 * 256 + j4);
        half4_t v5 = *(const half4_t*)(xwi + (long)s5 * 256 + j4);
        half4_t v6 = *(const half4_t*)(xwi + (long)s6 * 256 + j4);
        half4_t v7 = *(const half4_t*)(xwi + (long)s7 * 256 + j4);
        a0 += (float)v0[0] + (float)v1[0] + (float)v2[0] + (float)v3[0]
            + (float)v4[0] + (float)v5[0] + (float)v6[0] + (float)v7[0];
        a1 += (float)v0[1] + (float)v1[1] + (float)v2[1] + (float)v3[1]
            + (float)v4[1] + (float)v5[1] + (float)v6[1] + (float)v7[1];
        a2 += (float)v0[2] + (float)v1[2] + (float)v2[2] + (float)v3[2]
            + (float)v4[2] + (float)v5[2] + (float)v6[2] + (float)v7[2];
        a3 += (float)v0[3] + (float)v1[3] + (float)v2[3] + (float)v3[3]
            + (float)v4[3] + (float)v5[3] + (float)v6[3] + (float)v7[3];
    }
    for (; e + 4 <= e1; e += 4) {
        int s0 = col[e + 0], s1 = col[e + 1], s2 = col[e + 2], s3 = col[e + 3];
        half4_t v0 = *(const half4_t*)(xwi + (long)s0 * 256 + j4);
        half4_t v1 = *(const half4_t*)(xwi + (long)s1 * 256 + j4);
        half4_t v2 = *(const half4_t*)(xwi + (long)s2 * 256 + j4);
        half4_t v3 = *(const half4_t*)(xwi + (long)s3 * 256 + j4);
        a0 += (float)v0[0] + (float)v1[0] + (float)v2[0] + (float)v3[0];
        a1 += (float)v0[1] + (float)v1[1] + (float)v2[1] + (float)v3[1];
        a2 += (float)v0[2] + (float)v1[2] + (float)v2[2] + (float)v3[2];
        a3 += (float)v0[3] + (float)v1[3] + (float)v2[3] + (float)v3[3];
    }
    for (; e < e1; e++) {
        int s = col[e];
        half4_t v = *(const half4_t*)(xwi + (long)s * 256 + j4);
        a0 += (float)v[0]; a1 += (float)v[1]; a2 += (float)v[2]; a3 += (float)v[3];
    }
    float di = dinv[i];
    int jj = (lane < 32) ? j4 : (j4 - 128);
    const f32x4* bp = (const f32x4*)(bias + jj);
    f32x4 bv = *bp;
    f32x4 o;
    o[0] = fmaxf(0.f, di * a0 + bv[0]);
    o[1] = fmaxf(0.f, di * a1 + bv[1]);
    o[2] = fmaxf(0.f, di * a2 + bv[2]);
    o[3] = fmaxf(0.f, di * a3 + bv[3]);
    float* dst = ((lane < 32) ? pos_out : neg_out) + (long)i * D + jj;
    __builtin_nontemporal_store(o, (f32x4*)dst);
}

// ---------------- K6: summary mean over pos_h ----------------
__launch_bounds__(256)
__global__ void k_sum(const float* __restrict__ pos1, const float* __restrict__ pos2,
                      float* s1, float* s2) {
    int g = blockIdx.y;
    const float* pos = g ? pos2 : pos1;
    float* s = g ? s2 : s1;
    int t = threadIdx.x;
    int rg = t >> 5;
    int j = (t & 31) * 4;
    float4 acc = {0.f, 0.f, 0.f, 0.f};
    for (int i = blockIdx.x * 8 + rg; i < NN; i += gridDim.x * 8) {
        float4 v = *(const float4*)(pos + (long)i * D + j);
        acc.x += v.x; acc.y += v.y; acc.z += v.z; acc.w += v.w;
    }
    __shared__ float sm[8][128];
    sm[rg][j + 0] = acc.x;
    sm[rg][j + 1] = acc.y;
    sm[rg][j + 2] = acc.z;
    sm[rg][j + 3] = acc.w;
    __syncthreads();
    if (t < 128) {
        float v = 0.f;
        for (int r = 0; r < 8; r++) v += sm[r][t];
        atomicAdd(&s[t], v * (1.0f / NN));
    }
}

extern "C" void kernel_launch(void* const* d_in, const int* in_sizes, int n_in,
                              void* d_out, int out_size, void* d_ws, size_t ws_size,
                              hipStream_t stream) {
    const float* x   = (const float*)d_in[0];
    const float* W1  = (const float*)d_in[1];
    const float* b1  = (const float*)d_in[2];
    const float* W2  = (const float*)d_in[3];
    const float* b2  = (const float*)d_in[4];
    const float* mp1 = (const float*)d_in[5];
    const float* mn1 = (const float*)d_in[6];
    const float* mp2 = (const float*)d_in[7];
    const float* mn2 = (const float*)d_in[8];
    const int* e1 = (const int*)d_in[9];
    const int* e2 = (const int*)d_in[10];
    const int* perm1 = (const int*)d_in[11];
    const int* perm2 = (const int*)d_in[12];
    const int* src1 = e1;       const int* dst1 = e1 + NE;
    const int* src2 = e2;       const int* dst2 = e2 + NE;
    float* out = (float*)d_out;

    // workspace carve
    char* w = (char*)d_ws;
    _Float16* xwi1 = (_Float16*)w; w += (size_t)NN * 256 * 2;  // 25.6 MB interleaved
    _Float16* xwi2 = (_Float16*)w; w += (size_t)NN * 256 * 2;
    int* cnt1 = (int*)w;  w += (size_t)NN * 4;
    int* cnt2 = (int*)w;  w += (size_t)NN * 4;
    int* cur1 = (int*)w;  w += (size_t)NN * 4;
    int* cur2 = (int*)w;  w += (size_t)NN * 4;
    int* rp1 = (int*)w;   w += (size_t)(NN + 4) * 4;
    int* rp2 = (int*)w;   w += (size_t)(NN + 4) * 4;
    int* col1 = (int*)w;  w += (size_t)NE * 4;
    int* col2 = (int*)w;  w += (size_t)NE * 4;
    float* dinv1 = (float*)w; w += (size_t)NN * 4;
    float* dinv2 = (float*)w; w += (size_t)NN * 4;
    int* part1 = (int*)w; w += (size_t)256 * 4;
    int* part2 = (int*)w; w += (size_t)256 * 4;
    int* bcnt  = (int*)w; w += (size_t)64 * 4;
    int* bs1 = (int*)w;   w += (size_t)8 * BCAP * 4;   // 4 MB each
    int* bd1 = (int*)w;   w += (size_t)8 * BCAP * 4;
    int* bs2 = (int*)w;   w += (size_t)8 * BCAP * 4;
    int* bd2 = (int*)w;   w += (size_t)8 * BCAP * 4;

    float* s1 = out + 12800000L;
    float* s2 = out + 25600128L;
    const float* pos1 = out;
    const float* pos2 = out + 12800128L;

    k_init<<<dim3(256), 256, 0, stream>>>(cnt1, cnt2, s1, s2, bcnt);
    k_bucket<<<dim3(1024), 256, 0, stream>>>(src1, dst1, src2, dst2, bcnt,
                                             bs1, bd1, bs2, bd2);
    k_count_b<<<dim3(1024), 256, 0, stream>>>(bcnt, bd1, bd2, cnt1, cnt2);
    k_part<<<dim3(NB), 256, 0, stream>>>(cnt1, cnt2, part1, part2);
    k_scanp<<<dim3(1), 256, 0, stream>>>(part1, part2);
    k_apply<<<dim3(NB), 256, 0, stream>>>(cnt1, cnt2, part1, part2,
                                          rp1, rp2, cur1, cur2, dinv1, dinv2);
    k_fill_gemm<<<dim3(FILL_BLOCKS + GEMM_BLOCKS), 256, 0, stream>>>(
        bcnt, bs1, bd1, bs2, bd2, cur1, cur2, col1, col2,
        x, W1, W2, mp1, mn1, mp2, mn2, perm1, perm2, dinv1, dinv2, xwi1, xwi2);
    k_agg<<<dim3(12500, 2), 256, 0, stream>>>(xwi1, xwi2,
                                              rp1, col1, dinv1, rp2, col2, dinv2,
                                              b1, b2, out);
    k_sum<<<dim3(128, 2), 256, 0, stream>>>(pos1, pos2, s1, s2);
}

// Round 6
// 475.363 us; speedup vs baseline: 1.1742x; 1.1142x over previous
//
#include <hip/hip_runtime.h>
#include <hip/hip_fp16.h>

#define NN 50000
#define NE 800000
#define D 128
#define FILL_BLOCKS 1024
#define GEMM_BLOCKS 3128   // 782 * 4
#define NBKT 64       // fine dst buckets
#define BW 782        // bucket width (64*782 = 50048 >= NN)
#define BCAP 16384    // per-bucket capacity (expected ~12.5K, sigma ~112)

typedef _Float16 half8_t __attribute__((ext_vector_type(8)));
typedef _Float16 half4_t __attribute__((ext_vector_type(4)));
typedef float f32x4 __attribute__((ext_vector_type(4)));

// ---------------- K0: init summary slots + bucket counters ----------------
__global__ void k_init(float* s1, float* s2, int* bcnt) {
    int i = threadIdx.x;
    if (i < D) { s1[i] = 0.f; s2[i] = 0.f; }
    if (i < 2 * NBKT) bcnt[i] = 0;
}

// ---------------- K1: bucket edges into 64 fine dst-ranges (each edge read ONCE) ----------------
// LDS-aggregated counts -> 128 global atomics per block. Downstream passes read only
// their bucket, zero discard, and (crucially) the histogram becomes LDS-local per bucket.
__global__ void k_bucket(const int* __restrict__ src1, const int* __restrict__ dst1,
                         const int* __restrict__ src2, const int* __restrict__ dst2,
                         int* bcnt,
                         int* bs1, int* bd1, int* bs2, int* bd2) {
    __shared__ int lcnt[128], lpos[128], gbase[128];
    int t = threadIdx.x;
    if (t < 128) { lcnt[t] = 0; lpos[t] = 0; }
    __syncthreads();

    int e0 = blockIdx.x * 256 + t;
    int s1v0=0,d1v0=0,s2v0=0,d2v0=0, s1v1=0,d1v1=0,s2v1=0,d2v1=0;
    int s1v2=0,d1v2=0,s2v2=0,d2v2=0, s1v3=0,d1v3=0,s2v3=0,d2v3=0;
    bool v0 = (e0 + 0 * 262144) < NE;
    bool v1 = (e0 + 1 * 262144) < NE;
    bool v2 = (e0 + 2 * 262144) < NE;
    bool v3 = (e0 + 3 * 262144) < NE;
    if (v0) { int e = e0;             s1v0 = src1[e]; d1v0 = dst1[e]; s2v0 = src2[e]; d2v0 = dst2[e]; }
    if (v1) { int e = e0 + 262144;    s1v1 = src1[e]; d1v1 = dst1[e]; s2v1 = src2[e]; d2v1 = dst2[e]; }
    if (v2) { int e = e0 + 2*262144;  s1v2 = src1[e]; d1v2 = dst1[e]; s2v2 = src2[e]; d2v2 = dst2[e]; }
    if (v3) { int e = e0 + 3*262144;  s1v3 = src1[e]; d1v3 = dst1[e]; s2v3 = src2[e]; d2v3 = dst2[e]; }

    if (v0) { atomicAdd(&lcnt[d1v0 / BW], 1); atomicAdd(&lcnt[NBKT + d2v0 / BW], 1); }
    if (v1) { atomicAdd(&lcnt[d1v1 / BW], 1); atomicAdd(&lcnt[NBKT + d2v1 / BW], 1); }
    if (v2) { atomicAdd(&lcnt[d1v2 / BW], 1); atomicAdd(&lcnt[NBKT + d2v2 / BW], 1); }
    if (v3) { atomicAdd(&lcnt[d1v3 / BW], 1); atomicAdd(&lcnt[NBKT + d2v3 / BW], 1); }
    __syncthreads();
    if (t < 128) gbase[t] = atomicAdd(&bcnt[t], lcnt[t]);
    __syncthreads();

    #define PLACE(sv, dv) { \
        int r = (dv) / BW; \
        int p = gbase[r] + atomicAdd(&lpos[r], 1); \
        if (p < BCAP) { bs1[r * BCAP + p] = (sv); bd1[r * BCAP + p] = (dv); } }
    #define PLACE2(sv, dv) { \
        int r = (dv) / BW; \
        int p = gbase[NBKT + r] + atomicAdd(&lpos[NBKT + r], 1); \
        if (p < BCAP) { bs2[r * BCAP + p] = (sv); bd2[r * BCAP + p] = (dv); } }
    if (v0) { PLACE(s1v0, d1v0); PLACE2(s2v0, d2v0); }
    if (v1) { PLACE(s1v1, d1v1); PLACE2(s2v1, d2v1); }
    if (v2) { PLACE(s1v2, d1v2); PLACE2(s2v2, d2v2); }
    if (v3) { PLACE(s1v3, d1v3); PLACE2(s2v3, d2v3); }
    #undef PLACE
    #undef PLACE2
}

// ---------------- K2: per-bucket LDS histogram + in-LDS scan -> rp, cur, dinv ----------------
// Replaces global-atomic count (1.6M global atomics) + 3-kernel scan chain with ONE kernel:
// 128 blocks, one per (graph,bucket). All histogram atomics are LDS (random over 782
// counters -> conflict-free); bucket base comes directly from bcnt prefix.
__global__ void k_hist(const int* __restrict__ bcnt,
                       const int* __restrict__ bd1, const int* __restrict__ bd2,
                       int* rp1, int* rp2, int* cur1, int* cur2,
                       float* dinv1, float* dinv2) {
    __shared__ int h[1024];
    __shared__ int tsum[256];
    __shared__ int tb[64];
    __shared__ int bbase;
    int t = threadIdx.x;
    int g = blockIdx.x >> 6;         // graph
    int f = blockIdx.x & 63;         // bucket (XCD f&7 under round-robin, matches fill)
    const int* bd = g ? bd2 : bd1;
    int* rp = g ? rp2 : rp1;
    int* cur = g ? cur2 : cur1;
    float* dinv = g ? dinv2 : dinv1;
    int n = bcnt[g * NBKT + f];
    if (n > BCAP) n = BCAP;

    h[t] = 0; h[t + 256] = 0; h[t + 512] = 0; h[t + 768] = 0;
    if (t < NBKT) tb[t] = bcnt[g * NBKT + t];
    __syncthreads();

    const int* bdf = bd + f * BCAP;
    for (int i = t; i < n; i += 256) atomicAdd(&h[bdf[i] - f * BW], 1);
    if (t == 0) { int b = 0; for (int j = 0; j < f; j++) b += tb[j]; bbase = b; }
    __syncthreads();

    int a0 = h[4*t], a1 = h[4*t+1], a2 = h[4*t+2], a3 = h[4*t+3];
    int s = a0 + a1 + a2 + a3;
    tsum[t] = s;
    __syncthreads();
    for (int off = 1; off < 256; off <<= 1) {
        int add = (t >= off) ? tsum[t - off] : 0;
        __syncthreads();
        tsum[t] += add;
        __syncthreads();
    }
    int excl = tsum[t] - s + bbase;   // exclusive prefix for entry 4t (incl. bucket base)

    int idx = 4 * t;
    int gd = f * BW + idx;
    int e0 = excl, e1 = excl + a0, e2 = excl + a0 + a1, e3 = excl + a0 + a1 + a2;
    if (idx + 0 < BW && gd + 0 < NN) { rp[gd+0] = e0; cur[gd+0] = e0; dinv[gd+0] = rsqrtf((float)(a0+1)); }
    if (idx + 1 < BW && gd + 1 < NN) { rp[gd+1] = e1; cur[gd+1] = e1; dinv[gd+1] = rsqrtf((float)(a1+1)); }
    if (idx + 2 < BW && gd + 2 < NN) { rp[gd+2] = e2; cur[gd+2] = e2; dinv[gd+2] = rsqrtf((float)(a2+1)); }
    if (idx + 3 < BW && gd + 3 < NN) { rp[gd+3] = e3; cur[gd+3] = e3; dinv[gd+3] = rsqrtf((float)(a3+1)); }
    if (f == 63 && t == 0) rp[NN] = NE;
}

// ---------------- K3+K4 merged: fill-first (blocks 0..1023), then 4 GEMMs ----------------
// Dispatch structure + gemm body = R2 exact (measured best). Fill reads fine buckets:
// 16 blocks per bucket, bid&7 == f&7 keeps cur/col atomics XCD-local.
__launch_bounds__(256)
__global__ void k_fill_gemm(const int* __restrict__ bcnt,
                            const int* __restrict__ bs1, const int* __restrict__ bd1,
                            const int* __restrict__ bs2, const int* __restrict__ bd2,
                            int* cur1, int* cur2, int* col1, int* col2,
                            const float* __restrict__ x,
                            const float* __restrict__ W1, const float* __restrict__ W2,
                            const float* __restrict__ mp1, const float* __restrict__ mn1,
                            const float* __restrict__ mp2, const float* __restrict__ mn2,
                            const int* __restrict__ perm1, const int* __restrict__ perm2,
                            const float* __restrict__ dinv1, const float* __restrict__ dinv2,
                            _Float16* xwi1, _Float16* xwi2) {
    __shared__ __align__(16) _Float16 WT[128][136];   // 34816 B -> 4 blocks/CU
    int t = threadIdx.x;
    int bid = blockIdx.x;

    if (bid < FILL_BLOCKS) {
        int f = (bid & 7) + 8 * ((bid >> 3) & 7);   // fine bucket; f&7 == bid&7 (XCD-local)
        int rank = bid >> 6;                        // 0..15 (16 blocks per bucket)
        int base = f * BCAP;
        int n1 = bcnt[f];         if (n1 > BCAP) n1 = BCAP;
        int n2 = bcnt[NBKT + f];  if (n2 > BCAP) n2 = BCAP;
        for (int i = rank * 256 + t; i < n1; i += 4096) {
            int d = bd1[base + i];
            int p = atomicAdd(&cur1[d], 1);
            col1[p] = bs1[base + i];
        }
        for (int i = rank * 256 + t; i < n2; i += 4096) {
            int d = bd2[base + i];
            int p = atomicAdd(&cur2[d], 1);
            col2[p] = bs2[base + i];
        }
        return;
    }

    // ---- GEMM block (R2-exact body) ----
    int g = bid - FILL_BLOCKS;             // 0..3127
    int which = g / 782;                   // 0 = pos1, 1 = neg1, 2 = pos2, 3 = neg2
    int bx = g - which * 782;
    const float* W = (which < 2) ? W1 : W2;
    const float* mask = (which == 0) ? mp1 : (which == 1) ? mn1 : (which == 2) ? mp2 : mn2;
    const int* perm = (which == 1) ? perm1 : (which == 3) ? perm2 : nullptr;
    const float* dinv = (which < 2) ? dinv1 : dinv2;
    _Float16* out = ((which < 2) ? xwi1 : xwi2) + ((which & 1) ? 128 : 0);

    // W staging: column-chunk loads (coalesced) + half8 16B LDS writes (conflict-free).
    #pragma unroll
    for (int i = 0; i < 8; i++) {
        int idx = i * 256 + t;            // 0..2047
        int j = idx & 127;
        int k0 = (idx >> 7) * 8;          // 0,8,...,120
        half8_t h;
        #pragma unroll
        for (int c = 0; c < 8; c++) h[c] = (_Float16)W[(k0 + c) * 128 + j];
        *(half8_t*)(&WT[j][k0]) = h;      // WT[n][k], fp16
    }
    __syncthreads();

    int wave = t >> 6;
    int lane = t & 63;
    int quad = lane >> 4;
    int m = lane & 15;
    int tile = bx * 4 + wave;
    bool active = (tile * 16 < NN);       // no early return: barrier below

    f32x4 accs[8];
    if (active) {
        int row = tile * 16 + m;
        int grow = perm ? perm[row] : row;
        const float* xrow = x + (long)grow * D;
        const float* mrow = mask + (long)grow * D;

        half8_t a[4];
        #pragma unroll
        for (int kk = 0; kk < 4; kk++) {
            int k0 = kk * 32 + quad * 8;
            float4 xa = *(const float4*)(xrow + k0);
            float4 xb = *(const float4*)(xrow + k0 + 4);
            float4 ma = *(const float4*)(mrow + k0);
            float4 mb = *(const float4*)(mrow + k0 + 4);
            a[kk][0] = (_Float16)(xa.x * ma.x);
            a[kk][1] = (_Float16)(xa.y * ma.y);
            a[kk][2] = (_Float16)(xa.z * ma.z);
            a[kk][3] = (_Float16)(xa.w * ma.w);
            a[kk][4] = (_Float16)(xb.x * mb.x);
            a[kk][5] = (_Float16)(xb.y * mb.y);
            a[kk][6] = (_Float16)(xb.z * mb.z);
            a[kk][7] = (_Float16)(xb.w * mb.w);
        }

        // Swapped operands: A = W-fragment (out-col), B = x-fragment (x-row).
        #pragma unroll
        for (int nt = 0; nt < 8; nt++) {
            f32x4 acc = {0.f, 0.f, 0.f, 0.f};
            #pragma unroll
            for (int kk = 0; kk < 4; kk++) {
                half8_t w = *(const half8_t*)(&WT[nt * 16 + m][kk * 32 + quad * 8]);
                acc = __builtin_amdgcn_mfma_f32_16x16x32_f16(w, a[kk], acc, 0, 0, 0);
            }
            accs[nt] = acc;
        }
    }

    // All waves done reading WT -> reuse it as per-wave transpose staging.
    __syncthreads();

    if (active) {
        float ds = dinv[tile * 16 + m];   // one row per lane
        _Float16* st = &WT[0][0] + wave * 2176;   // 16 rows x 136 halves per wave

        #pragma unroll
        for (int nt = 0; nt < 8; nt++) {
            half4_t h;
            h[0] = (_Float16)(accs[nt][0] * ds);
            h[1] = (_Float16)(accs[nt][1] * ds);
            h[2] = (_Float16)(accs[nt][2] * ds);
            h[3] = (_Float16)(accs[nt][3] * ds);
            *(half4_t*)(st + m * 136 + nt * 16 + quad * 4) = h;
        }
        // Read back row-contiguous; every store instr = 16 rows x 64B full aligned lines.
        #pragma unroll
        for (int p = 0; p < 4; p++) {
            int r = lane & 15;
            int cc = (lane >> 4) + p * 4;       // 16B chunk index 0..15
            half8_t v = *(const half8_t*)(st + r * 136 + cc * 8);
            *(half8_t*)(out + (long)(tile * 16 + r) * 256 + cc * 8) = v;
        }
    }
}

// ---------------- K5: CSR gather aggregation + bias + ReLU (no atomics) ----------------
__launch_bounds__(256)
__global__ void k_agg(const _Float16* __restrict__ xwi1, const _Float16* __restrict__ xwi2,
                      const int* __restrict__ rp1, const int* __restrict__ col1,
                      const float* __restrict__ dinv1,
                      const int* __restrict__ rp2, const int* __restrict__ col2,
                      const float* __restrict__ dinv2,
                      const float* __restrict__ b1, const float* __restrict__ b2,
                      float* out) {
    int g = blockIdx.y;
    const _Float16* xwi = g ? xwi2 : xwi1;
    const int* rp = g ? rp2 : rp1;
    const int* col = g ? col2 : col1;
    const float* dinv = g ? dinv2 : dinv1;
    const float* bias = g ? b2 : b1;
    float* pos_out = out + (g ? 12800128L : 0L);
    float* neg_out = out + (g ? 19200128L : 6400000L);

    int t = threadIdx.x;
    int wave = t >> 6, lane = t & 63;
    int i = blockIdx.x * 4 + wave;
    if (i >= NN) return;
    int j4 = lane * 4;

    half4_t sv = *(const half4_t*)(xwi + (long)i * 256 + j4);
    float a0 = (float)sv[0], a1 = (float)sv[1], a2 = (float)sv[2], a3 = (float)sv[3];
    int e0 = rp[i], e1 = rp[i + 1];
    int e = e0;
    for (; e + 8 <= e1; e += 8) {
        int s0 = col[e + 0], s1 = col[e + 1], s2 = col[e + 2], s3 = col[e + 3];
        int s4 = col[e + 4], s5 = col[e + 5], s6 = col[e + 6], s7 = col[e + 7];
        half4_t v0 = *(const half4_t*)(xwi + (long)s0 * 256 + j4);
        half4_t v1 = *(const half4_t*)(xwi + (long)s1 * 256 + j4);
        half4_t v2 = *(const half4_t*)(xwi + (long)s2 * 256 + j4);
        half4_t v3 = *(const half4_t*)(xwi + (long)s3 * 256 + j4);
        half4_t v4 = *(const half4_t*)(xwi + (long)s4 * 256 + j4);
        half4_t v5 = *(const half4_t*)(xwi + (long)s5 * 256 + j4);
        half4_t v6 = *(const half4_t*)(xwi + (long)s6 * 256 + j4);
        half4_t v7 = *(const half4_t*)(xwi + (long)s7 * 256 + j4);
        a0 += (float)v0[0] + (float)v1[0] + (float)v2[0] + (float)v3[0]
            + (float)v4[0] + (float)v5[0] + (float)v6[0] + (float)v7[0];
        a1 += (float)v0[1] + (float)v1[1] + (float)v2[1] + (float)v3[1]
            + (float)v4[1] + (float)v5[1] + (float)v6[1] + (float)v7[1];
        a2 += (float)v0[2] + (float)v1[2] + (float)v2[2] + (float)v3[2]
            + (float)v4[2] + (float)v5[2] + (float)v6[2] + (float)v7[2];
        a3 += (float)v0[3] + (float)v1[3] + (float)v2[3] + (float)v3[3]
            + (float)v4[3] + (float)v5[3] + (float)v6[3] + (float)v7[3];
    }
    for (; e + 4 <= e1; e += 4) {
        int s0 = col[e + 0], s1 = col[e + 1], s2 = col[e + 2], s3 = col[e + 3];
        half4_t v0 = *(const half4_t*)(xwi + (long)s0 * 256 + j4);
        half4_t v1 = *(const half4_t*)(xwi + (long)s1 * 256 + j4);
        half4_t v2 = *(const half4_t*)(xwi + (long)s2 * 256 + j4);
        half4_t v3 = *(const half4_t*)(xwi + (long)s3 * 256 + j4);
        a0 += (float)v0[0] + (float)v1[0] + (float)v2[0] + (float)v3[0];
        a1 += (float)v0[1] + (float)v1[1] + (float)v2[1] + (float)v3[1];
        a2 += (float)v0[2] + (float)v1[2] + (float)v2[2] + (float)v3[2];
        a3 += (float)v0[3] + (float)v1[3] + (float)v2[3] + (float)v3[3];
    }
    for (; e < e1; e++) {
        int s = col[e];
        half4_t v = *(const half4_t*)(xwi + (long)s * 256 + j4);
        a0 += (float)v[0]; a1 += (float)v[1]; a2 += (float)v[2]; a3 += (float)v[3];
    }
    float di = dinv[i];
    int jj = (lane < 32) ? j4 : (j4 - 128);
    const f32x4* bp = (const f32x4*)(bias + jj);
    f32x4 bv = *bp;
    f32x4 o;
    o[0] = fmaxf(0.f, di * a0 + bv[0]);
    o[1] = fmaxf(0.f, di * a1 + bv[1]);
    o[2] = fmaxf(0.f, di * a2 + bv[2]);
    o[3] = fmaxf(0.f, di * a3 + bv[3]);
    float* dst = ((lane < 32) ? pos_out : neg_out) + (long)i * D + jj;
    __builtin_nontemporal_store(o, (f32x4*)dst);
}

// ---------------- K6: summary mean over pos_h ----------------
__launch_bounds__(256)
__global__ void k_sum(const float* __restrict__ pos1, const float* __restrict__ pos2,
                      float* s1, float* s2) {
    int g = blockIdx.y;
    const float* pos = g ? pos2 : pos1;
    float* s = g ? s2 : s1;
    int t = threadIdx.x;
    int rg = t >> 5;
    int j = (t & 31) * 4;
    float4 acc = {0.f, 0.f, 0.f, 0.f};
    for (int i = blockIdx.x * 8 + rg; i < NN; i += gridDim.x * 8) {
        float4 v = *(const float4*)(pos + (long)i * D + j);
        acc.x += v.x; acc.y += v.y; acc.z += v.z; acc.w += v.w;
    }
    __shared__ float sm[8][128];
    sm[rg][j + 0] = acc.x;
    sm[rg][j + 1] = acc.y;
    sm[rg][j + 2] = acc.z;
    sm[rg][j + 3] = acc.w;
    __syncthreads();
    if (t < 128) {
        float v = 0.f;
        for (int r = 0; r < 8; r++) v += sm[r][t];
        atomicAdd(&s[t], v * (1.0f / NN));
    }
}

extern "C" void kernel_launch(void* const* d_in, const int* in_sizes, int n_in,
                              void* d_out, int out_size, void* d_ws, size_t ws_size,
                              hipStream_t stream) {
    const float* x   = (const float*)d_in[0];
    const float* W1  = (const float*)d_in[1];
    const float* b1  = (const float*)d_in[2];
    const float* W2  = (const float*)d_in[3];
    const float* b2  = (const float*)d_in[4];
    const float* mp1 = (const float*)d_in[5];
    const float* mn1 = (const float*)d_in[6];
    const float* mp2 = (const float*)d_in[7];
    const float* mn2 = (const float*)d_in[8];
    const int* e1 = (const int*)d_in[9];
    const int* e2 = (const int*)d_in[10];
    const int* perm1 = (const int*)d_in[11];
    const int* perm2 = (const int*)d_in[12];
    const int* src1 = e1;       const int* dst1 = e1 + NE;
    const int* src2 = e2;       const int* dst2 = e2 + NE;
    float* out = (float*)d_out;

    // workspace carve
    char* w = (char*)d_ws;
    _Float16* xwi1 = (_Float16*)w; w += (size_t)NN * 256 * 2;  // 25.6 MB interleaved
    _Float16* xwi2 = (_Float16*)w; w += (size_t)NN * 256 * 2;
    int* cur1 = (int*)w;  w += (size_t)NN * 4;
    int* cur2 = (int*)w;  w += (size_t)NN * 4;
    int* rp1 = (int*)w;   w += (size_t)(NN + 4) * 4;
    int* rp2 = (int*)w;   w += (size_t)(NN + 4) * 4;
    int* col1 = (int*)w;  w += (size_t)NE * 4;
    int* col2 = (int*)w;  w += (size_t)NE * 4;
    float* dinv1 = (float*)w; w += (size_t)NN * 4;
    float* dinv2 = (float*)w; w += (size_t)NN * 4;
    int* bcnt  = (int*)w; w += (size_t)128 * 4;
    int* bs1 = (int*)w;   w += (size_t)NBKT * BCAP * 4;   // 4 MB each
    int* bd1 = (int*)w;   w += (size_t)NBKT * BCAP * 4;
    int* bs2 = (int*)w;   w += (size_t)NBKT * BCAP * 4;
    int* bd2 = (int*)w;   w += (size_t)NBKT * BCAP * 4;

    float* s1 = out + 12800000L;
    float* s2 = out + 25600128L;
    const float* pos1 = out;
    const float* pos2 = out + 12800128L;

    k_init<<<dim3(1), 256, 0, stream>>>(s1, s2, bcnt);
    k_bucket<<<dim3(1024), 256, 0, stream>>>(src1, dst1, src2, dst2, bcnt,
                                             bs1, bd1, bs2, bd2);
    k_hist<<<dim3(128), 256, 0, stream>>>(bcnt, bd1, bd2,
                                          rp1, rp2, cur1, cur2, dinv1, dinv2);
    k_fill_gemm<<<dim3(FILL_BLOCKS + GEMM_BLOCKS), 256, 0, stream>>>(
        bcnt, bs1, bd1, bs2, bd2, cur1, cur2, col1, col2,
        x, W1, W2, mp1, mn1, mp2, mn2, perm1, perm2, dinv1, dinv2, xwi1, xwi2);
    k_agg<<<dim3(12500, 2), 256, 0, stream>>>(xwi1, xwi2,
                                              rp1, col1, dinv1, rp2, col2, dinv2,
                                              b1, b2, out);
    k_sum<<<dim3(128, 2), 256, 0, stream>>>(pos1, pos2, s1, s2);
}

// Round 7
// 465.628 us; speedup vs baseline: 1.1988x; 1.0209x over previous
//
#include <hip/hip_runtime.h>
#include <hip/hip_fp16.h>

#define NN 50000
#define NE 800000
#define D 128
#define GEMM_BLOCKS 3128   // 782 * 4
#define NBKT 64       // fine dst buckets per graph
#define BW 782        // bucket width (64*782 = 50048 >= NN)
#define BCAP 16384    // per-bucket capacity (expected ~12.5K, sigma ~112)

typedef _Float16 half8_t __attribute__((ext_vector_type(8)));
typedef _Float16 half4_t __attribute__((ext_vector_type(4)));
typedef float f32x4 __attribute__((ext_vector_type(4)));

// ---------------- K0: init summary + bucket counters + W transpose to half ----------------
// wt[n][k] = (half)W[k][n]: gemm loads w-fragments directly from this L2-resident 32KB.
__global__ void k_init(float* s1, float* s2, int* bcnt,
                       const float* __restrict__ W1, const float* __restrict__ W2,
                       _Float16* wt1, _Float16* wt2) {
    int i = blockIdx.x * 256 + threadIdx.x;   // grid 64*256 = 16384 exactly
    if (i < D) { s1[i] = 0.f; s2[i] = 0.f; }
    if (i < 2 * NBKT) bcnt[i] = 0;
    int n = i >> 7, k = i & 127;
    wt1[n * 128 + k] = (_Float16)W1[k * 128 + n];
    wt2[n * 128 + k] = (_Float16)W2[k * 128 + n];
}

// ---------------- K1: bucket edges into 64 fine dst-ranges (each edge read ONCE) ----------------
__global__ void k_bucket(const int* __restrict__ src1, const int* __restrict__ dst1,
                         const int* __restrict__ src2, const int* __restrict__ dst2,
                         int* bcnt,
                         int* bs1, int* bd1, int* bs2, int* bd2) {
    __shared__ int lcnt[128], lpos[128], gbase[128];
    int t = threadIdx.x;
    if (t < 128) { lcnt[t] = 0; lpos[t] = 0; }
    __syncthreads();

    int e0 = blockIdx.x * 256 + t;
    int s1v0=0,d1v0=0,s2v0=0,d2v0=0, s1v1=0,d1v1=0,s2v1=0,d2v1=0;
    int s1v2=0,d1v2=0,s2v2=0,d2v2=0, s1v3=0,d1v3=0,s2v3=0,d2v3=0;
    bool v0 = (e0 + 0 * 262144) < NE;
    bool v1 = (e0 + 1 * 262144) < NE;
    bool v2 = (e0 + 2 * 262144) < NE;
    bool v3 = (e0 + 3 * 262144) < NE;
    if (v0) { int e = e0;             s1v0 = src1[e]; d1v0 = dst1[e]; s2v0 = src2[e]; d2v0 = dst2[e]; }
    if (v1) { int e = e0 + 262144;    s1v1 = src1[e]; d1v1 = dst1[e]; s2v1 = src2[e]; d2v1 = dst2[e]; }
    if (v2) { int e = e0 + 2*262144;  s1v2 = src1[e]; d1v2 = dst1[e]; s2v2 = src2[e]; d2v2 = dst2[e]; }
    if (v3) { int e = e0 + 3*262144;  s1v3 = src1[e]; d1v3 = dst1[e]; s2v3 = src2[e]; d2v3 = dst2[e]; }

    if (v0) { atomicAdd(&lcnt[d1v0 / BW], 1); atomicAdd(&lcnt[NBKT + d2v0 / BW], 1); }
    if (v1) { atomicAdd(&lcnt[d1v1 / BW], 1); atomicAdd(&lcnt[NBKT + d2v1 / BW], 1); }
    if (v2) { atomicAdd(&lcnt[d1v2 / BW], 1); atomicAdd(&lcnt[NBKT + d2v2 / BW], 1); }
    if (v3) { atomicAdd(&lcnt[d1v3 / BW], 1); atomicAdd(&lcnt[NBKT + d2v3 / BW], 1); }
    __syncthreads();
    if (t < 128) gbase[t] = atomicAdd(&bcnt[t], lcnt[t]);
    __syncthreads();

    #define PLACE(sv, dv) { \
        int r = (dv) / BW; \
        int p = gbase[r] + atomicAdd(&lpos[r], 1); \
        if (p < BCAP) { bs1[r * BCAP + p] = (sv); bd1[r * BCAP + p] = (dv); } }
    #define PLACE2(sv, dv) { \
        int r = (dv) / BW; \
        int p = gbase[NBKT + r] + atomicAdd(&lpos[NBKT + r], 1); \
        if (p < BCAP) { bs2[r * BCAP + p] = (sv); bd2[r * BCAP + p] = (dv); } }
    if (v0) { PLACE(s1v0, d1v0); PLACE2(s2v0, d2v0); }
    if (v1) { PLACE(s1v1, d1v1); PLACE2(s2v1, d2v1); }
    if (v2) { PLACE(s1v2, d1v2); PLACE2(s2v2, d2v2); }
    if (v3) { PLACE(s1v3, d1v3); PLACE2(s2v3, d2v3); }
    #undef PLACE
    #undef PLACE2
}

// ---------------- K2: build CSR per bucket entirely in LDS ----------------
// One block per (graph,bucket). Histogram (LDS atomics over 782 counters) -> in-LDS
// exclusive scan -> rp/dinv -> convert histogram slots to absolute cursors -> place pass
// fills col[] via LDS atomics. ZERO global atomics; col writes land in one contiguous
// ~50KB CSR span per block (the bucket's dsts are contiguous in CSR order).
__launch_bounds__(512)
__global__ void k_build(const int* __restrict__ bcnt,
                        const int* __restrict__ bs1, const int* __restrict__ bd1,
                        const int* __restrict__ bs2, const int* __restrict__ bd2,
                        int* rp1, int* rp2, int* col1, int* col2,
                        float* dinv1, float* dinv2) {
    __shared__ int h[1024];
    __shared__ int tsum[512];
    __shared__ int tb[64];
    __shared__ int bbase;
    int t = threadIdx.x;
    int g = blockIdx.x >> 6;         // graph
    int f = blockIdx.x & 63;         // bucket
    const int* bd = (g ? bd2 : bd1) + f * BCAP;
    const int* bs = (g ? bs2 : bs1) + f * BCAP;
    int* rp = g ? rp2 : rp1;
    int* col = g ? col2 : col1;
    float* dinv = g ? dinv2 : dinv1;
    int n = bcnt[g * NBKT + f];
    if (n > BCAP) n = BCAP;

    h[t] = 0; h[t + 512] = 0;
    if (t < NBKT) tb[t] = bcnt[g * NBKT + t];
    __syncthreads();

    for (int i = t; i < n; i += 512) atomicAdd(&h[bd[i] - f * BW], 1);
    __syncthreads();
    if (t == 0) { int b = 0; for (int j = 0; j < f; j++) b += tb[j]; bbase = b; }

    int a0 = h[2 * t], a1 = h[2 * t + 1];
    int s = a0 + a1;
    tsum[t] = s;
    __syncthreads();
    for (int off = 1; off < 512; off <<= 1) {
        int add = (t >= off) ? tsum[t - off] : 0;
        __syncthreads();
        tsum[t] += add;
        __syncthreads();
    }
    int excl = tsum[t] - s + bbase;   // absolute col offset for local dst 2t
    int idx = 2 * t, gd = f * BW + idx;
    int e0 = excl, e1 = excl + a0;
    h[2 * t] = e0; h[2 * t + 1] = e1;     // histogram slots become absolute cursors
    if (idx < BW && gd < NN)         { rp[gd]     = e0; dinv[gd]     = rsqrtf((float)(a0 + 1)); }
    if (idx + 1 < BW && gd + 1 < NN) { rp[gd + 1] = e1; dinv[gd + 1] = rsqrtf((float)(a1 + 1)); }
    if (f == 63 && t == 0) rp[NN] = NE;
    __syncthreads();

    for (int i = t; i < n; i += 512) {
        int p = atomicAdd(&h[bd[i] - f * BW], 1);   // LDS cursor
        col[p] = bs[i];
    }
}

// ---------------- K3: 4 GEMMs standalone (R3-verified staging-free body) ----------------
// w-fragments direct from global wt (L2-resident); per-wave LDS transpose scratch only
// (17.4KB -> 8 blocks/CU); no barriers -> early return safe.
__launch_bounds__(256)
__global__ void k_gemm(const _Float16* __restrict__ wt1, const _Float16* __restrict__ wt2,
                       const float* __restrict__ x,
                       const float* __restrict__ mp1, const float* __restrict__ mn1,
                       const float* __restrict__ mp2, const float* __restrict__ mn2,
                       const int* __restrict__ perm1, const int* __restrict__ perm2,
                       const float* __restrict__ dinv1, const float* __restrict__ dinv2,
                       _Float16* xwi1, _Float16* xwi2) {
    __shared__ __align__(16) _Float16 ST[4][16][136];   // per-wave private transpose scratch

    int g = blockIdx.x;                    // 0..3127
    int which = g / 782;                   // 0 = pos1, 1 = neg1, 2 = pos2, 3 = neg2
    int bx = g - which * 782;
    const _Float16* wt = (which < 2) ? wt1 : wt2;
    const float* mask = (which == 0) ? mp1 : (which == 1) ? mn1 : (which == 2) ? mp2 : mn2;
    const int* perm = (which == 1) ? perm1 : (which == 3) ? perm2 : nullptr;
    const float* dinv = (which < 2) ? dinv1 : dinv2;
    _Float16* out = ((which < 2) ? xwi1 : xwi2) + ((which & 1) ? 128 : 0);

    int t = threadIdx.x;
    int wave = t >> 6;
    int lane = t & 63;
    int quad = lane >> 4;
    int m = lane & 15;
    int tile = bx * 4 + wave;
    if (tile * 16 >= NN) return;           // no barriers anywhere -> safe early return

    int row = tile * 16 + m;
    int grow = perm ? perm[row] : row;
    const float* xrow = x + (long)grow * D;
    const float* mrow = mask + (long)grow * D;

    half8_t a[4];
    #pragma unroll
    for (int kk = 0; kk < 4; kk++) {
        int k0 = kk * 32 + quad * 8;
        float4 xa = *(const float4*)(xrow + k0);
        float4 xb = *(const float4*)(xrow + k0 + 4);
        float4 ma = *(const float4*)(mrow + k0);
        float4 mb = *(const float4*)(mrow + k0 + 4);
        a[kk][0] = (_Float16)(xa.x * ma.x);
        a[kk][1] = (_Float16)(xa.y * ma.y);
        a[kk][2] = (_Float16)(xa.z * ma.z);
        a[kk][3] = (_Float16)(xa.w * ma.w);
        a[kk][4] = (_Float16)(xb.x * mb.x);
        a[kk][5] = (_Float16)(xb.y * mb.y);
        a[kk][6] = (_Float16)(xb.z * mb.z);
        a[kk][7] = (_Float16)(xb.w * mb.w);
    }

    // Swapped operands: A = W-fragment (out-col), B = x-fragment (x-row).
    f32x4 accs[8];
    #pragma unroll
    for (int nt = 0; nt < 8; nt++) {
        const _Float16* wrow = wt + (nt * 16 + m) * 128 + quad * 8;
        f32x4 acc = {0.f, 0.f, 0.f, 0.f};
        #pragma unroll
        for (int kk = 0; kk < 4; kk++) {
            half8_t w = *(const half8_t*)(wrow + kk * 32);
            acc = __builtin_amdgcn_mfma_f32_16x16x32_f16(w, a[kk], acc, 0, 0, 0);
        }
        accs[nt] = acc;
    }

    // Per-wave LDS transpose epilogue (wave-private slice -> no sync needed).
    float ds = dinv[tile * 16 + m];        // one row per lane
    _Float16* st = &ST[wave][0][0];

    #pragma unroll
    for (int nt = 0; nt < 8; nt++) {
        half4_t h;
        h[0] = (_Float16)(accs[nt][0] * ds);
        h[1] = (_Float16)(accs[nt][1] * ds);
        h[2] = (_Float16)(accs[nt][2] * ds);
        h[3] = (_Float16)(accs[nt][3] * ds);
        *(half4_t*)(st + m * 136 + nt * 16 + quad * 4) = h;
    }
    // Read back row-contiguous; every store instr = 16 rows x 64B full aligned lines.
    #pragma unroll
    for (int p = 0; p < 4; p++) {
        int r = lane & 15;
        int cc = (lane >> 4) + p * 4;       // 16B chunk index 0..15
        half8_t v = *(const half8_t*)(st + r * 136 + cc * 8);
        *(half8_t*)(out + (long)(tile * 16 + r) * 256 + cc * 8) = v;
    }
}

// ---------------- K5: CSR gather aggregation + bias + ReLU (no atomics) ----------------
__launch_bounds__(256)
__global__ void k_agg(const _Float16* __restrict__ xwi1, const _Float16* __restrict__ xwi2,
                      const int* __restrict__ rp1, const int* __restrict__ col1,
                      const float* __restrict__ dinv1,
                      const int* __restrict__ rp2, const int* __restrict__ col2,
                      const float* __restrict__ dinv2,
                      const float* __restrict__ b1, const float* __restrict__ b2,
                      float* out) {
    int g = blockIdx.y;
    const _Float16* xwi = g ? xwi2 : xwi1;
    const int* rp = g ? rp2 : rp1;
    const int* col = g ? col2 : col1;
    const float* dinv = g ? dinv2 : dinv1;
    const float* bias = g ? b2 : b1;
    float* pos_out = out + (g ? 12800128L : 0L);
    float* neg_out = out + (g ? 19200128L : 6400000L);

    int t = threadIdx.x;
    int wave = t >> 6, lane = t & 63;
    int i = blockIdx.x * 4 + wave;
    if (i >= NN) return;
    int j4 = lane * 4;

    half4_t sv = *(const half4_t*)(xwi + (long)i * 256 + j4);
    float a0 = (float)sv[0], a1 = (float)sv[1], a2 = (float)sv[2], a3 = (float)sv[3];
    int e0 = rp[i], e1 = rp[i + 1];
    int e = e0;
    for (; e + 8 <= e1; e += 8) {
        int s0 = col[e + 0], s1 = col[e + 1], s2 = col[e + 2], s3 = col[e + 3];
        int s4 = col[e + 4], s5 = col[e + 5], s6 = col[e + 6], s7 = col[e + 7];
        half4_t v0 = *(const half4_t*)(xwi + (long)s0 * 256 + j4);
        half4_t v1 = *(const half4_t*)(xwi + (long)s1 * 256 + j4);
        half4_t v2 = *(const half4_t*)(xwi + (long)s2 * 256 + j4);
        half4_t v3 = *(const half4_t*)(xwi + (long)s3 * 256 + j4);
        half4_t v4 = *(const half4_t*)(xwi + (long)s4 * 256 + j4);
        half4_t v5 = *(const half4_t*)(xwi + (long)s5 * 256 + j4);
        half4_t v6 = *(const half4_t*)(xwi + (long)s6 * 256 + j4);
        half4_t v7 = *(const half4_t*)(xwi + (long)s7 * 256 + j4);
        a0 += (float)v0[0] + (float)v1[0] + (float)v2[0] + (float)v3[0]
            + (float)v4[0] + (float)v5[0] + (float)v6[0] + (float)v7[0];
        a1 += (float)v0[1] + (float)v1[1] + (float)v2[1] + (float)v3[1]
            + (float)v4[1] + (float)v5[1] + (float)v6[1] + (float)v7[1];
        a2 += (float)v0[2] + (float)v1[2] + (float)v2[2] + (float)v3[2]
            + (float)v4[2] + (float)v5[2] + (float)v6[2] + (float)v7[2];
        a3 += (float)v0[3] + (float)v1[3] + (float)v2[3] + (float)v3[3]
            + (float)v4[3] + (float)v5[3] + (float)v6[3] + (float)v7[3];
    }
    for (; e + 4 <= e1; e += 4) {
        int s0 = col[e + 0], s1 = col[e + 1], s2 = col[e + 2], s3 = col[e + 3];
        half4_t v0 = *(const half4_t*)(xwi + (long)s0 * 256 + j4);
        half4_t v1 = *(const half4_t*)(xwi + (long)s1 * 256 + j4);
        half4_t v2 = *(const half4_t*)(xwi + (long)s2 * 256 + j4);
        half4_t v3 = *(const half4_t*)(xwi + (long)s3 * 256 + j4);
        a0 += (float)v0[0] + (float)v1[0] + (float)v2[0] + (float)v3[0];
        a1 += (float)v0[1] + (float)v1[1] + (float)v2[1] + (float)v3[1];
        a2 += (float)v0[2] + (float)v1[2] + (float)v2[2] + (float)v3[2];
        a3 += (float)v0[3] + (float)v1[3] + (float)v2[3] + (float)v3[3];
    }
    for (; e < e1; e++) {
        int s = col[e];
        half4_t v = *(const half4_t*)(xwi + (long)s * 256 + j4);
        a0 += (float)v[0]; a1 += (float)v[1]; a2 += (float)v[2]; a3 += (float)v[3];
    }
    float di = dinv[i];
    int jj = (lane < 32) ? j4 : (j4 - 128);
    const f32x4* bp = (const f32x4*)(bias + jj);
    f32x4 bv = *bp;
    f32x4 o;
    o[0] = fmaxf(0.f, di * a0 + bv[0]);
    o[1] = fmaxf(0.f, di * a1 + bv[1]);
    o[2] = fmaxf(0.f, di * a2 + bv[2]);
    o[3] = fmaxf(0.f, di * a3 + bv[3]);
    float* dst = ((lane < 32) ? pos_out : neg_out) + (long)i * D + jj;
    __builtin_nontemporal_store(o, (f32x4*)dst);
}

// ---------------- K6: summary mean over pos_h ----------------
__launch_bounds__(256)
__global__ void k_sum(const float* __restrict__ pos1, const float* __restrict__ pos2,
                      float* s1, float* s2) {
    int g = blockIdx.y;
    const float* pos = g ? pos2 : pos1;
    float* s = g ? s2 : s1;
    int t = threadIdx.x;
    int rg = t >> 5;
    int j = (t & 31) * 4;
    float4 acc = {0.f, 0.f, 0.f, 0.f};
    for (int i = blockIdx.x * 8 + rg; i < NN; i += gridDim.x * 8) {
        float4 v = *(const float4*)(pos + (long)i * D + j);
        acc.x += v.x; acc.y += v.y; acc.z += v.z; acc.w += v.w;
    }
    __shared__ float sm[8][128];
    sm[rg][j + 0] = acc.x;
    sm[rg][j + 1] = acc.y;
    sm[rg][j + 2] = acc.z;
    sm[rg][j + 3] = acc.w;
    __syncthreads();
    if (t < 128) {
        float v = 0.f;
        for (int r = 0; r < 8; r++) v += sm[r][t];
        atomicAdd(&s[t], v * (1.0f / NN));
    }
}

extern "C" void kernel_launch(void* const* d_in, const int* in_sizes, int n_in,
                              void* d_out, int out_size, void* d_ws, size_t ws_size,
                              hipStream_t stream) {
    const float* x   = (const float*)d_in[0];
    const float* W1  = (const float*)d_in[1];
    const float* b1  = (const float*)d_in[2];
    const float* W2  = (const float*)d_in[3];
    const float* b2  = (const float*)d_in[4];
    const float* mp1 = (const float*)d_in[5];
    const float* mn1 = (const float*)d_in[6];
    const float* mp2 = (const float*)d_in[7];
    const float* mn2 = (const float*)d_in[8];
    const int* e1 = (const int*)d_in[9];
    const int* e2 = (const int*)d_in[10];
    const int* perm1 = (const int*)d_in[11];
    const int* perm2 = (const int*)d_in[12];
    const int* src1 = e1;       const int* dst1 = e1 + NE;
    const int* src2 = e2;       const int* dst2 = e2 + NE;
    float* out = (float*)d_out;

    // workspace carve
    char* w = (char*)d_ws;
    _Float16* xwi1 = (_Float16*)w; w += (size_t)NN * 256 * 2;  // 25.6 MB interleaved
    _Float16* xwi2 = (_Float16*)w; w += (size_t)NN * 256 * 2;
    int* rp1 = (int*)w;   w += (size_t)(NN + 4) * 4;
    int* rp2 = (int*)w;   w += (size_t)(NN + 4) * 4;
    int* col1 = (int*)w;  w += (size_t)NE * 4;
    int* col2 = (int*)w;  w += (size_t)NE * 4;
    float* dinv1 = (float*)w; w += (size_t)NN * 4;
    float* dinv2 = (float*)w; w += (size_t)NN * 4;
    int* bcnt  = (int*)w; w += (size_t)128 * 4;
    int* bs1 = (int*)w;   w += (size_t)NBKT * BCAP * 4;   // 4 MB each
    int* bd1 = (int*)w;   w += (size_t)NBKT * BCAP * 4;
    int* bs2 = (int*)w;   w += (size_t)NBKT * BCAP * 4;
    int* bd2 = (int*)w;   w += (size_t)NBKT * BCAP * 4;
    _Float16* wt1 = (_Float16*)w; w += (size_t)D * D * 2; // 32 KB transposed half W1
    _Float16* wt2 = (_Float16*)w; w += (size_t)D * D * 2;

    float* s1 = out + 12800000L;
    float* s2 = out + 25600128L;
    const float* pos1 = out;
    const float* pos2 = out + 12800128L;

    k_init<<<dim3(64), 256, 0, stream>>>(s1, s2, bcnt, W1, W2, wt1, wt2);
    k_bucket<<<dim3(1024), 256, 0, stream>>>(src1, dst1, src2, dst2, bcnt,
                                             bs1, bd1, bs2, bd2);
    k_build<<<dim3(128), 512, 0, stream>>>(bcnt, bs1, bd1, bs2, bd2,
                                           rp1, rp2, col1, col2, dinv1, dinv2);
    k_gemm<<<dim3(GEMM_BLOCKS), 256, 0, stream>>>(wt1, wt2,
        x, mp1, mn1, mp2, mn2, perm1, perm2, dinv1, dinv2, xwi1, xwi2);
    k_agg<<<dim3(12500, 2), 256, 0, stream>>>(xwi1, xwi2,
                                              rp1, col1, dinv1, rp2, col2, dinv2,
                                              b1, b2, out);
    k_sum<<<dim3(128, 2), 256, 0, stream>>>(pos1, pos2, s1, s2);
}

// Round 8
// 453.252 us; speedup vs baseline: 1.2315x; 1.0273x over previous
//
#include <hip/hip_runtime.h>
#include <hip/hip_fp16.h>

#define NN 50000
#define NE 800000
#define D 128
#define GEMM_BLOCKS 3128   // 782 * 4
#define NBKT 64       // fine dst buckets per graph
#define BW 782        // bucket width (64*782 = 50048 >= NN)
#define BCAP 16384    // per-bucket capacity (expected ~12.5K, sigma ~112)

typedef _Float16 half8_t __attribute__((ext_vector_type(8)));
typedef _Float16 half4_t __attribute__((ext_vector_type(4)));
typedef float f32x4 __attribute__((ext_vector_type(4)));

// ---------------- K0: init bcnt + summary slices + W transpose + inverse perms ----------------
__global__ void k_init(float* ssl, int* bcnt,
                       const float* __restrict__ W1, const float* __restrict__ W2,
                       _Float16* wt1, _Float16* wt2,
                       const int* __restrict__ perm1, const int* __restrict__ perm2,
                       int* pinv1, int* pinv2) {
    int i = blockIdx.x * 256 + threadIdx.x;   // grid 196*256 = 50176
    if (i < NN) { pinv1[perm1[i]] = i; pinv2[perm2[i]] = i; }
    if (i < 2 * NBKT) bcnt[i] = 0;
    if (i < 16384) {
        ssl[i] = 0.f;                          // 2 graphs * 64 slices * 128 cols
        int n = i >> 7, k = i & 127;
        wt1[n * 128 + k] = (_Float16)W1[k * 128 + n];
        wt2[n * 128 + k] = (_Float16)W2[k * 128 + n];
    }
}

// ---------------- K1: bucket edges into 64 fine dst-ranges (int2-packed, one 8B store) ----------------
__global__ void k_bucket(const int* __restrict__ src1, const int* __restrict__ dst1,
                         const int* __restrict__ src2, const int* __restrict__ dst2,
                         int* bcnt, int2* bsd1, int2* bsd2) {
    __shared__ int lcnt[128], lpos[128], gbase[128];
    int t = threadIdx.x;
    if (t < 128) { lcnt[t] = 0; lpos[t] = 0; }
    __syncthreads();

    int e0 = blockIdx.x * 256 + t;
    int s1v0=0,d1v0=0,s2v0=0,d2v0=0, s1v1=0,d1v1=0,s2v1=0,d2v1=0;
    int s1v2=0,d1v2=0,s2v2=0,d2v2=0, s1v3=0,d1v3=0,s2v3=0,d2v3=0;
    bool v0 = (e0 + 0 * 262144) < NE;
    bool v1 = (e0 + 1 * 262144) < NE;
    bool v2 = (e0 + 2 * 262144) < NE;
    bool v3 = (e0 + 3 * 262144) < NE;
    if (v0) { int e = e0;             s1v0 = src1[e]; d1v0 = dst1[e]; s2v0 = src2[e]; d2v0 = dst2[e]; }
    if (v1) { int e = e0 + 262144;    s1v1 = src1[e]; d1v1 = dst1[e]; s2v1 = src2[e]; d2v1 = dst2[e]; }
    if (v2) { int e = e0 + 2*262144;  s1v2 = src1[e]; d1v2 = dst1[e]; s2v2 = src2[e]; d2v2 = dst2[e]; }
    if (v3) { int e = e0 + 3*262144;  s1v3 = src1[e]; d1v3 = dst1[e]; s2v3 = src2[e]; d2v3 = dst2[e]; }

    if (v0) { atomicAdd(&lcnt[d1v0 / BW], 1); atomicAdd(&lcnt[NBKT + d2v0 / BW], 1); }
    if (v1) { atomicAdd(&lcnt[d1v1 / BW], 1); atomicAdd(&lcnt[NBKT + d2v1 / BW], 1); }
    if (v2) { atomicAdd(&lcnt[d1v2 / BW], 1); atomicAdd(&lcnt[NBKT + d2v2 / BW], 1); }
    if (v3) { atomicAdd(&lcnt[d1v3 / BW], 1); atomicAdd(&lcnt[NBKT + d2v3 / BW], 1); }
    __syncthreads();
    if (t < 128) gbase[t] = atomicAdd(&bcnt[t], lcnt[t]);
    __syncthreads();

    #define PLACE(sv, dv) { \
        int r = (dv) / BW; \
        int p = gbase[r] + atomicAdd(&lpos[r], 1); \
        if (p < BCAP) bsd1[r * BCAP + p] = make_int2((sv), (dv)); }
    #define PLACE2(sv, dv) { \
        int r = (dv) / BW; \
        int p = gbase[NBKT + r] + atomicAdd(&lpos[NBKT + r], 1); \
        if (p < BCAP) bsd2[r * BCAP + p] = make_int2((sv), (dv)); }
    if (v0) { PLACE(s1v0, d1v0); PLACE2(s2v0, d2v0); }
    if (v1) { PLACE(s1v1, d1v1); PLACE2(s2v1, d2v1); }
    if (v2) { PLACE(s1v2, d1v2); PLACE2(s2v2, d2v2); }
    if (v3) { PLACE(s1v3, d1v3); PLACE2(s2v3, d2v3); }
    #undef PLACE
    #undef PLACE2
}

// ---------------- K2: build CSR per bucket entirely in LDS (zero global atomics) ----------------
__launch_bounds__(512)
__global__ void k_build(const int* __restrict__ bcnt,
                        const int2* __restrict__ bsd1, const int2* __restrict__ bsd2,
                        int* rp1, int* rp2, int* col1, int* col2,
                        float* dinv1, float* dinv2) {
    __shared__ int h[1024];
    __shared__ int tsum[512];
    __shared__ int tb[64];
    __shared__ int bbase;
    int t = threadIdx.x;
    int g = blockIdx.x >> 6;         // graph
    int f = blockIdx.x & 63;         // bucket
    const int2* bsd = (g ? bsd2 : bsd1) + f * BCAP;
    int* rp = g ? rp2 : rp1;
    int* col = g ? col2 : col1;
    float* dinv = g ? dinv2 : dinv1;
    int n = bcnt[g * NBKT + f];
    if (n > BCAP) n = BCAP;

    h[t] = 0; h[t + 512] = 0;
    if (t < NBKT) tb[t] = bcnt[g * NBKT + t];
    __syncthreads();

    for (int i = t; i < n; i += 512) atomicAdd(&h[bsd[i].y - f * BW], 1);
    __syncthreads();
    if (t == 0) { int b = 0; for (int j = 0; j < f; j++) b += tb[j]; bbase = b; }

    int a0 = h[2 * t], a1 = h[2 * t + 1];
    int s = a0 + a1;
    tsum[t] = s;
    __syncthreads();
    for (int off = 1; off < 512; off <<= 1) {
        int add = (t >= off) ? tsum[t - off] : 0;
        __syncthreads();
        tsum[t] += add;
        __syncthreads();
    }
    int excl = tsum[t] - s + bbase;
    int idx = 2 * t, gd = f * BW + idx;
    int e0 = excl, e1 = excl + a0;
    h[2 * t] = e0; h[2 * t + 1] = e1;     // histogram slots become absolute cursors
    if (idx < BW && gd < NN)         { rp[gd]     = e0; dinv[gd]     = rsqrtf((float)(a0 + 1)); }
    if (idx + 1 < BW && gd + 1 < NN) { rp[gd + 1] = e1; dinv[gd + 1] = rsqrtf((float)(a1 + 1)); }
    if (f == 63 && t == 0) rp[NN] = NE;
    __syncthreads();

    for (int i = t; i < n; i += 512) {
        int2 e = bsd[i];
        int p = atomicAdd(&h[e.y - f * BW], 1);   // LDS cursor
        col[p] = e.x;
    }
}

// ---------------- K3: 4 GEMMs, all branches stream x/mask in NATURAL order ----------------
// Neg branches no longer gather x[perm[row]] (102MB random reads): compute natural row q,
// scatter output to row pinv[q]. x now gets 4x L3 reuse; masks are single-use streams ->
// nontemporal loads (no L2 pollution). R3-verified body otherwise (direct-W, no barriers).
__launch_bounds__(256)
__global__ void k_gemm(const _Float16* __restrict__ wt1, const _Float16* __restrict__ wt2,
                       const float* __restrict__ x,
                       const float* __restrict__ mp1, const float* __restrict__ mn1,
                       const float* __restrict__ mp2, const float* __restrict__ mn2,
                       const int* __restrict__ pinv1, const int* __restrict__ pinv2,
                       const float* __restrict__ dinv1, const float* __restrict__ dinv2,
                       _Float16* xwi1, _Float16* xwi2) {
    __shared__ __align__(16) _Float16 ST[4][16][136];   // per-wave private transpose scratch

    int g = blockIdx.x;                    // 0..3127
    int which = g / 782;                   // 0 = pos1, 1 = neg1, 2 = pos2, 3 = neg2
    int bx = g - which * 782;
    const _Float16* wt = (which < 2) ? wt1 : wt2;
    const float* mask = (which == 0) ? mp1 : (which == 1) ? mn1 : (which == 2) ? mp2 : mn2;
    const int* pinv = (which == 1) ? pinv1 : (which == 3) ? pinv2 : nullptr;
    const float* dinv = (which < 2) ? dinv1 : dinv2;
    _Float16* out = ((which < 2) ? xwi1 : xwi2) + ((which & 1) ? 128 : 0);

    int t = threadIdx.x;
    int wave = t >> 6;
    int lane = t & 63;
    int quad = lane >> 4;
    int m = lane & 15;
    int tile = bx * 4 + wave;
    if (tile * 16 >= NN) return;           // no barriers -> safe early return

    int row = tile * 16 + m;               // natural compute row (streaming reads)
    const float* xrow = x + (long)row * D;
    const float* mrow = mask + (long)row * D;

    half8_t a[4];
    #pragma unroll
    for (int kk = 0; kk < 4; kk++) {
        int k0 = kk * 32 + quad * 8;
        f32x4 xa = *(const f32x4*)(xrow + k0);
        f32x4 xb = *(const f32x4*)(xrow + k0 + 4);
        f32x4 ma = __builtin_nontemporal_load((const f32x4*)(mrow + k0));
        f32x4 mb = __builtin_nontemporal_load((const f32x4*)(mrow + k0 + 4));
        a[kk][0] = (_Float16)(xa[0] * ma[0]);
        a[kk][1] = (_Float16)(xa[1] * ma[1]);
        a[kk][2] = (_Float16)(xa[2] * ma[2]);
        a[kk][3] = (_Float16)(xa[3] * ma[3]);
        a[kk][4] = (_Float16)(xb[0] * mb[0]);
        a[kk][5] = (_Float16)(xb[1] * mb[1]);
        a[kk][6] = (_Float16)(xb[2] * mb[2]);
        a[kk][7] = (_Float16)(xb[3] * mb[3]);
    }

    // Swapped operands: A = W-fragment (out-col), B = x-fragment (x-row).
    f32x4 accs[8];
    #pragma unroll
    for (int nt = 0; nt < 8; nt++) {
        const _Float16* wrow = wt + (nt * 16 + m) * 128 + quad * 8;
        f32x4 acc = {0.f, 0.f, 0.f, 0.f};
        #pragma unroll
        for (int kk = 0; kk < 4; kk++) {
            half8_t w = *(const half8_t*)(wrow + kk * 32);
            acc = __builtin_amdgcn_mfma_f32_16x16x32_f16(w, a[kk], acc, 0, 0, 0);
        }
        accs[nt] = acc;
    }

    // Output row: natural for pos, pinv-scattered for neg (m == lane&15 -> one lookup).
    int orow = pinv ? pinv[row] : row;
    float ds = dinv[orow];
    _Float16* st = &ST[wave][0][0];

    #pragma unroll
    for (int nt = 0; nt < 8; nt++) {
        half4_t h;
        h[0] = (_Float16)(accs[nt][0] * ds);
        h[1] = (_Float16)(accs[nt][1] * ds);
        h[2] = (_Float16)(accs[nt][2] * ds);
        h[3] = (_Float16)(accs[nt][3] * ds);
        *(half4_t*)(st + m * 136 + nt * 16 + quad * 4) = h;
    }
    // Read back row-contiguous: each lane stores 16B chunks of ITS row orow (full 64B lines).
    #pragma unroll
    for (int p = 0; p < 4; p++) {
        int cc = (lane >> 4) + p * 4;       // 16B chunk index 0..15
        half8_t v = *(const half8_t*)(st + m * 136 + cc * 8);
        *(half8_t*)(out + (long)orow * 256 + cc * 8) = v;
    }
}

// ---------------- K5: CSR gather aggregation + bias + ReLU + fused summary partials ----------------
__launch_bounds__(256)
__global__ void k_agg(const _Float16* __restrict__ xwi1, const _Float16* __restrict__ xwi2,
                      const int* __restrict__ rp1, const int* __restrict__ col1,
                      const float* __restrict__ dinv1,
                      const int* __restrict__ rp2, const int* __restrict__ col2,
                      const float* __restrict__ dinv2,
                      const float* __restrict__ b1, const float* __restrict__ b2,
                      float* out, float* ssl) {
    __shared__ float ssum[128];
    int g = blockIdx.y;
    const _Float16* xwi = g ? xwi2 : xwi1;
    const int* rp = g ? rp2 : rp1;
    const int* col = g ? col2 : col1;
    const float* dinv = g ? dinv2 : dinv1;
    const float* bias = g ? b2 : b1;
    float* pos_out = out + (g ? 12800128L : 0L);
    float* neg_out = out + (g ? 19200128L : 6400000L);

    int t = threadIdx.x;
    if (t < 128) ssum[t] = 0.f;
    __syncthreads();

    int wave = t >> 6, lane = t & 63;
    int i = blockIdx.x * 4 + wave;          // grid exact: 12500*4 == NN, no tail
    int j4 = lane * 4;

    half4_t sv = *(const half4_t*)(xwi + (long)i * 256 + j4);
    float a0 = (float)sv[0], a1 = (float)sv[1], a2 = (float)sv[2], a3 = (float)sv[3];
    int e0 = rp[i], e1 = rp[i + 1];
    int e = e0;
    for (; e + 8 <= e1; e += 8) {
        int s0 = col[e + 0], s1 = col[e + 1], s2 = col[e + 2], s3 = col[e + 3];
        int s4 = col[e + 4], s5 = col[e + 5], s6 = col[e + 6], s7 = col[e + 7];
        half4_t v0 = *(const half4_t*)(xwi + (long)s0 * 256 + j4);
        half4_t v1 = *(const half4_t*)(xwi + (long)s1 * 256 + j4);
        half4_t v2 = *(const half4_t*)(xwi + (long)s2 * 256 + j4);
        half4_t v3 = *(const half4_t*)(xwi + (long)s3 * 256 + j4);
        half4_t v4 = *(const half4_t*)(xwi + (long)s4 * 256 + j4);
        half4_t v5 = *(const half4_t*)(xwi + (long)s5 * 256 + j4);
        half4_t v6 = *(const half4_t*)(xwi + (long)s6 * 256 + j4);
        half4_t v7 = *(const half4_t*)(xwi + (long)s7 * 256 + j4);
        a0 += (float)v0[0] + (float)v1[0] + (float)v2[0] + (float)v3[0]
            + (float)v4[0] + (float)v5[0] + (float)v6[0] + (float)v7[0];
        a1 += (float)v0[1] + (float)v1[1] + (float)v2[1] + (float)v3[1]
            + (float)v4[1] + (float)v5[1] + (float)v6[1] + (float)v7[1];
        a2 += (float)v0[2] + (float)v1[2] + (float)v2[2] + (float)v3[2]
            + (float)v4[2] + (float)v5[2] + (float)v6[2] + (float)v7[2];
        a3 += (float)v0[3] + (float)v1[3] + (float)v2[3] + (float)v3[3]
            + (float)v4[3] + (float)v5[3] + (float)v6[3] + (float)v7[3];
    }
    for (; e + 4 <= e1; e += 4) {
        int s0 = col[e + 0], s1 = col[e + 1], s2 = col[e + 2], s3 = col[e + 3];
        half4_t v0 = *(const half4_t*)(xwi + (long)s0 * 256 + j4);
        half4_t v1 = *(const half4_t*)(xwi + (long)s1 * 256 + j4);
        half4_t v2 = *(const half4_t*)(xwi + (long)s2 * 256 + j4);
        half4_t v3 = *(const half4_t*)(xwi + (long)s3 * 256 + j4);
        a0 += (float)v0[0] + (float)v1[0] + (float)v2[0] + (float)v3[0];
        a1 += (float)v0[1] + (float)v1[1] + (float)v2[1] + (float)v3[1];
        a2 += (float)v0[2] + (float)v1[2] + (float)v2[2] + (float)v3[2];
        a3 += (float)v0[3] + (float)v1[3] + (float)v2[3] + (float)v3[3];
    }
    for (; e < e1; e++) {
        int s = col[e];
        half4_t v = *(const half4_t*)(xwi + (long)s * 256 + j4);
        a0 += (float)v[0]; a1 += (float)v[1]; a2 += (float)v[2]; a3 += (float)v[3];
    }
    float di = dinv[i];
    int jj = (lane < 32) ? j4 : (j4 - 128);
    const f32x4* bp = (const f32x4*)(bias + jj);
    f32x4 bv = *bp;
    f32x4 o;
    o[0] = fmaxf(0.f, di * a0 + bv[0]);
    o[1] = fmaxf(0.f, di * a1 + bv[1]);
    o[2] = fmaxf(0.f, di * a2 + bv[2]);
    o[3] = fmaxf(0.f, di * a3 + bv[3]);
    float* dst = ((lane < 32) ? pos_out : neg_out) + (long)i * D + jj;
    __builtin_nontemporal_store(o, (f32x4*)dst);

    // fused summary: pos lanes accumulate block partial in LDS, one slice-atomic per col
    if (lane < 32) {
        atomicAdd(&ssum[j4 + 0], o[0]);
        atomicAdd(&ssum[j4 + 1], o[1]);
        atomicAdd(&ssum[j4 + 2], o[2]);
        atomicAdd(&ssum[j4 + 3], o[3]);
    }
    __syncthreads();
    if (t < 128) atomicAdd(&ssl[(long)g * 8192 + (blockIdx.x & 63) * 128 + t], ssum[t]);
}

// ---------------- K6: reduce 64 summary slices -> s1/s2 (reads 64KB) ----------------
__global__ void k_sumf(const float* __restrict__ ssl, float* s1, float* s2) {
    int g = blockIdx.y;
    int t = threadIdx.x;          // 128 threads
    const float* p = ssl + (long)g * 8192;
    float v = 0.f;
    #pragma unroll
    for (int sl = 0; sl < 64; sl++) v += p[sl * 128 + t];
    (g ? s2 : s1)[t] = v * (1.0f / NN);
}

extern "C" void kernel_launch(void* const* d_in, const int* in_sizes, int n_in,
                              void* d_out, int out_size, void* d_ws, size_t ws_size,
                              hipStream_t stream) {
    const float* x   = (const float*)d_in[0];
    const float* W1  = (const float*)d_in[1];
    const float* b1  = (const float*)d_in[2];
    const float* W2  = (const float*)d_in[3];
    const float* b2  = (const float*)d_in[4];
    const float* mp1 = (const float*)d_in[5];
    const float* mn1 = (const float*)d_in[6];
    const float* mp2 = (const float*)d_in[7];
    const float* mn2 = (const float*)d_in[8];
    const int* e1 = (const int*)d_in[9];
    const int* e2 = (const int*)d_in[10];
    const int* perm1 = (const int*)d_in[11];
    const int* perm2 = (const int*)d_in[12];
    const int* src1 = e1;       const int* dst1 = e1 + NE;
    const int* src2 = e2;       const int* dst2 = e2 + NE;
    float* out = (float*)d_out;

    // workspace carve
    char* w = (char*)d_ws;
    _Float16* xwi1 = (_Float16*)w; w += (size_t)NN * 256 * 2;  // 25.6 MB interleaved
    _Float16* xwi2 = (_Float16*)w; w += (size_t)NN * 256 * 2;
    int* rp1 = (int*)w;   w += (size_t)(NN + 4) * 4;
    int* rp2 = (int*)w;   w += (size_t)(NN + 4) * 4;
    int* col1 = (int*)w;  w += (size_t)NE * 4;
    int* col2 = (int*)w;  w += (size_t)NE * 4;
    float* dinv1 = (float*)w; w += (size_t)NN * 4;
    float* dinv2 = (float*)w; w += (size_t)NN * 4;
    int* bcnt  = (int*)w; w += (size_t)128 * 4;
    int2* bsd1 = (int2*)w; w += (size_t)NBKT * BCAP * 8;   // 8 MB each
    int2* bsd2 = (int2*)w; w += (size_t)NBKT * BCAP * 8;
    _Float16* wt1 = (_Float16*)w; w += (size_t)D * D * 2;  // 32 KB transposed half W
    _Float16* wt2 = (_Float16*)w; w += (size_t)D * D * 2;
    int* pinv1 = (int*)w; w += (size_t)NN * 4;
    int* pinv2 = (int*)w; w += (size_t)NN * 4;
    float* ssl = (float*)w; w += (size_t)2 * 64 * 128 * 4; // summary slices

    float* s1 = out + 12800000L;
    float* s2 = out + 25600128L;

    k_init<<<dim3(196), 256, 0, stream>>>(ssl, bcnt, W1, W2, wt1, wt2,
                                          perm1, perm2, pinv1, pinv2);
    k_bucket<<<dim3(1024), 256, 0, stream>>>(src1, dst1, src2, dst2, bcnt, bsd1, bsd2);
    k_build<<<dim3(128), 512, 0, stream>>>(bcnt, bsd1, bsd2,
                                           rp1, rp2, col1, col2, dinv1, dinv2);
    k_gemm<<<dim3(GEMM_BLOCKS), 256, 0, stream>>>(wt1, wt2,
        x, mp1, mn1, mp2, mn2, pinv1, pinv2, dinv1, dinv2, xwi1, xwi2);
    k_agg<<<dim3(12500, 2), 256, 0, stream>>>(xwi1, xwi2,
                                              rp1, col1, dinv1, rp2, col2, dinv2,
                                              b1, b2, out, ssl);
    k_sumf<<<dim3(1, 2), 128, 0, stream>>>(ssl, s1, s2);
}